// Round 1
// baseline (1199.291 us; speedup 1.0000x reference)
//
#include <hip/hip_runtime.h>
#include <math.h>

// Problem constants
#define DMODEL 256
#define HEADS  8
#define HDIM   32
#define BS     4
#define NQ     100
#define NPTS   25
#define LQ     2500      // NQ*NPTS
#define M10K   10000     // BS*LQ
#define LEN_IN 21760
#define MVAL   87040     // BS*LEN_IN

// ---------------------------------------------------------------------------
// Generic fp32 GEMM: C[M,N] = A[M,K] @ W[N,K]^T + bias[N], optional relu.
// 128x128 tile, BK=16, 256 threads, 8x8 micro-tile per thread.
// N must be a multiple of 128 (grid.x = N/128). M edge guarded.
// ---------------------------------------------------------------------------
__global__ __launch_bounds__(256) void gemm_bias_kernel(
    const float* __restrict__ A, int lda,
    const float* __restrict__ W, int K,
    const float* __restrict__ bias,
    float* __restrict__ C, int ldc,
    int M, int relu)
{
    __shared__ float As[16][132];
    __shared__ float Ws[16][132];
    const int tid = threadIdx.x;
    const int tx = tid & 15, ty = tid >> 4;
    const int m0 = blockIdx.y * 128, n0 = blockIdx.x * 128;

    float acc[8][8];
#pragma unroll
    for (int i = 0; i < 8; ++i)
#pragma unroll
        for (int j = 0; j < 8; ++j) acc[i][j] = 0.f;

    for (int k0 = 0; k0 < K; k0 += 16) {
#pragma unroll
        for (int i = 0; i < 2; ++i) {
            int idx4 = tid + i * 256;          // 0..511
            int m = idx4 >> 2;                 // 0..127
            int kq = (idx4 & 3) * 4;           // 0,4,8,12
            int gm = m0 + m;
            float4 av = make_float4(0.f, 0.f, 0.f, 0.f);
            if (gm < M) av = *(const float4*)(A + (size_t)gm * lda + k0 + kq);
            As[kq + 0][m] = av.x; As[kq + 1][m] = av.y;
            As[kq + 2][m] = av.z; As[kq + 3][m] = av.w;
            float4 wv = *(const float4*)(W + (size_t)(n0 + m) * K + k0 + kq);
            Ws[kq + 0][m] = wv.x; Ws[kq + 1][m] = wv.y;
            Ws[kq + 2][m] = wv.z; Ws[kq + 3][m] = wv.w;
        }
        __syncthreads();
#pragma unroll
        for (int k = 0; k < 16; ++k) {
            float a[8], b[8];
#pragma unroll
            for (int i = 0; i < 8; ++i) a[i] = As[k][ty * 8 + i];
#pragma unroll
            for (int j = 0; j < 8; ++j) b[j] = Ws[k][tx * 8 + j];
#pragma unroll
            for (int i = 0; i < 8; ++i)
#pragma unroll
                for (int j = 0; j < 8; ++j)
                    acc[i][j] = fmaf(a[i], b[j], acc[i][j]);
        }
        __syncthreads();
    }

#pragma unroll
    for (int i = 0; i < 8; ++i) {
        int gm = m0 + ty * 8 + i;
        if (gm >= M) continue;
        float* crow = C + (size_t)gm * ldc + n0 + tx * 8;
        const float* brow = bias + n0 + tx * 8;
#pragma unroll
        for (int j = 0; j < 8; ++j) {
            float v = acc[i][j] + brow[j];
            if (relu) v = fmaxf(v, 0.f);
            crow[j] = v;
        }
    }
}

// ---------------------------------------------------------------------------
// Small MHA (per (batch,head) block): flash-style online softmax, one thread
// per query row. qkv layout: [nb, S, 768] with q@0, k@256, v@512, head h at
// +h*32. Output: [nb, S, 256], head h at cols h*32.
// ---------------------------------------------------------------------------
__global__ void small_attn_kernel(const float* __restrict__ qkv,
                                  float* __restrict__ out,
                                  int S, float scale)
{
    extern __shared__ float lds[];   // [S][64]: k (32) | v (32)
    const int b = blockIdx.x, h = blockIdx.y;
    const float* base = qkv + (size_t)b * S * 768;

    for (int idx = threadIdx.x; idx < S * 64; idx += blockDim.x) {
        int r = idx >> 6, c = idx & 63;
        float v = (c < 32) ? base[r * 768 + 256 + h * 32 + c]
                           : base[r * 768 + 512 + h * 32 + (c - 32)];
        lds[idx] = v;
    }
    __syncthreads();

    const int i = threadIdx.x;
    if (i < S) {
        float q[32];
        const float* qp = base + i * 768 + h * 32;
#pragma unroll
        for (int c = 0; c < 32; ++c) q[c] = qp[c];
        float m = -1e30f, l = 0.f, acc[32];
#pragma unroll
        for (int c = 0; c < 32; ++c) acc[c] = 0.f;
        for (int j = 0; j < S; ++j) {
            const float* kj = &lds[j * 64];
            float s = 0.f;
#pragma unroll
            for (int c = 0; c < 32; ++c) s = fmaf(q[c], kj[c], s);
            s *= scale;
            float mn = fmaxf(m, s);
            float alpha = __expf(m - mn);
            float p = __expf(s - mn);
            l = l * alpha + p;
            const float* vj = kj + 32;
#pragma unroll
            for (int c = 0; c < 32; ++c) acc[c] = acc[c] * alpha + p * vj[c];
            m = mn;
        }
        float inv = 1.f / l;
        float* op = out + ((size_t)b * S + i) * 256 + h * 32;
#pragma unroll
        for (int c = 0; c < 32; ++c) op[c] = acc[c] * inv;
    }
}

// ---------------------------------------------------------------------------
// out[row] = LN(a[row] + b[row]) * g + beta.  One wave (64 threads) per row of
// 256.  transpose_mode=1: row index r is in ti layout (bp*100+q, bp=b*25+p)
// and output goes to row (b*100+q)*25+p  (transpose back to tgt layout).
// ---------------------------------------------------------------------------
__global__ __launch_bounds__(64) void add_ln_kernel(
    const float* __restrict__ a, const float* __restrict__ b,
    const float* __restrict__ g, const float* __restrict__ beta,
    float* __restrict__ out, int transpose_mode)
{
    const int r = blockIdx.x;
    const int lane = threadIdx.x;
    const float* ar = a + (size_t)r * 256;
    const float* br = b + (size_t)r * 256;
    float x[4];
    float s = 0.f;
#pragma unroll
    for (int i = 0; i < 4; ++i) {
        x[i] = ar[lane + 64 * i] + br[lane + 64 * i];
        s += x[i];
    }
#pragma unroll
    for (int off = 32; off >= 1; off >>= 1) s += __shfl_xor(s, off);
    float mean = s * (1.f / 256.f);
    float vs = 0.f;
#pragma unroll
    for (int i = 0; i < 4; ++i) { float d = x[i] - mean; vs += d * d; }
#pragma unroll
    for (int off = 32; off >= 1; off >>= 1) vs += __shfl_xor(vs, off);
    float rstd = rsqrtf(vs * (1.f / 256.f) + 1e-5f);

    size_t ro = r;
    if (transpose_mode) {
        int q = r % 100; int bp = r / 100; int p = bp % 25; int bb = bp / 25;
        ro = ((size_t)bb * 100 + q) * 25 + p;
    }
    float* orow = out + ro * 256;
#pragma unroll
    for (int i = 0; i < 4; ++i) {
        int c = lane + 64 * i;
        orow[c] = (x[i] - mean) * rstd * g[c] + beta[c];
    }
}

// ---------------------------------------------------------------------------
// elementwise o = a + b (float4)
// ---------------------------------------------------------------------------
__global__ void add_vec4_kernel(const float4* __restrict__ a,
                                const float4* __restrict__ b,
                                float4* __restrict__ o, int n4)
{
    int i = blockIdx.x * blockDim.x + threadIdx.x;
    if (i < n4) {
        float4 x = a[i], y = b[i];
        o[i] = make_float4(x.x + y.x, x.y + y.y, x.z + y.z, x.w + y.w);
    }
}

// ---------------------------------------------------------------------------
// ti[(b*25+p)*100+q][:] = tgt1[(b*100+q)*25+p][:]
// ---------------------------------------------------------------------------
__global__ __launch_bounds__(64) void tgt_to_ti_kernel(
    const float* __restrict__ tgt1, float* __restrict__ ti)
{
    const int r = blockIdx.x;              // ti row
    int q = r % 100; int bp = r / 100; int p = bp % 25; int b = bp / 25;
    const float4* srcp = (const float4*)(tgt1 + (((size_t)b * 100 + q) * 25 + p) * 256);
    float4* dstp = (float4*)(ti + (size_t)r * 256);
    dstp[threadIdx.x] = srcp[threadIdx.x];
}

// ---------------------------------------------------------------------------
// MSDeform sampling. One block per (b, lq); thread = (h = tid>>5, c = tid&31).
// value: [BS, LEN_IN, 8, 32]; off: [BS, LQ, 256]; awl: [BS, LQ, 128] (logits);
// refp: [BS, NQ, 4, 2]; out sampled: [BS, LQ, 256]  (head h at cols h*32).
// ---------------------------------------------------------------------------
__global__ __launch_bounds__(256) void msdeform_sample_kernel(
    const float* __restrict__ value,
    const float* __restrict__ off,
    const float* __restrict__ awl,
    const float* __restrict__ refp,
    float* __restrict__ sampled)
{
    const int blk = blockIdx.x;
    const int b = blk / LQ, lq = blk - b * LQ;
    const int q = lq / NPTS;
    const int h = threadIdx.x >> 5, c = threadIdx.x & 31;

    // attention-weight softmax over 16 (redundant across the 32 lanes of h)
    const float* awp = awl + ((size_t)b * LQ + lq) * 128 + h * 16;
    float w[16];
    float mx = -1e30f;
#pragma unroll
    for (int t = 0; t < 16; ++t) { w[t] = awp[t]; mx = fmaxf(mx, w[t]); }
    float sum = 0.f;
#pragma unroll
    for (int t = 0; t < 16; ++t) { w[t] = __expf(w[t] - mx); sum += w[t]; }
    const float inv = 1.f / sum;

    const float* offp = off + ((size_t)b * LQ + lq) * 256 + h * 32;
    const float* rp = refp + ((size_t)b * 100 + q) * 8;
    const float* vb = value + (size_t)b * LEN_IN * 256 + h * 32 + c;

    float acc = 0.f;
    int start = 0;
    const int sz[4] = {128, 64, 32, 16};
#pragma unroll
    for (int l = 0; l < 4; ++l) {
        const int hh = sz[l], ww = sz[l];
        const float rx = rp[l * 2 + 0], ry = rp[l * 2 + 1];
#pragma unroll
        for (int pt = 0; pt < 4; ++pt) {
            float ox = offp[(l * 4 + pt) * 2 + 0];
            float oy = offp[(l * 4 + pt) * 2 + 1];
            float x = rx * ww + ox - 0.5f;       // == (rx + ox/ww)*ww - 0.5
            float y = ry * hh + oy - 0.5f;
            float x0f = floorf(x), y0f = floorf(y);
            float wx = x - x0f, wy = y - y0f;
            int x0 = (int)x0f, y0 = (int)y0f;
            int x1 = x0 + 1, y1 = y0 + 1;
            float aw = w[l * 4 + pt] * inv;

            // corner fetch with zero-pad boundary, clipped index
            int x0c = min(max(x0, 0), ww - 1), x1c = min(max(x1, 0), ww - 1);
            int y0c = min(max(y0, 0), hh - 1), y1c = min(max(y1, 0), hh - 1);
            float m00 = (x0 >= 0 && x0 < ww && y0 >= 0 && y0 < hh) ? 1.f : 0.f;
            float m10 = (x1 >= 0 && x1 < ww && y0 >= 0 && y0 < hh) ? 1.f : 0.f;
            float m01 = (x0 >= 0 && x0 < ww && y1 >= 0 && y1 < hh) ? 1.f : 0.f;
            float m11 = (x1 >= 0 && x1 < ww && y1 >= 0 && y1 < hh) ? 1.f : 0.f;
            float v00 = vb[(size_t)(start + y0c * ww + x0c) * 256] * m00;
            float v10 = vb[(size_t)(start + y0c * ww + x1c) * 256] * m10;
            float v01 = vb[(size_t)(start + y1c * ww + x0c) * 256] * m01;
            float v11 = vb[(size_t)(start + y1c * ww + x1c) * 256] * m11;

            acc += aw * (v00 * (1.f - wx) * (1.f - wy)
                       + v10 * wx * (1.f - wy)
                       + v01 * (1.f - wx) * wy
                       + v11 * wx * wy);
        }
        start += hh * ww;
    }
    sampled[((size_t)b * LQ + lq) * 256 + h * 32 + c] = acc;
}

// ---------------------------------------------------------------------------
extern "C" void kernel_launch(void* const* d_in, const int* in_sizes, int n_in,
                              void* d_out, int out_size, void* d_ws, size_t ws_size,
                              hipStream_t stream)
{
    (void)in_sizes; (void)n_in; (void)out_size; (void)ws_size;

    const float* tgt        = (const float*)d_in[0];
    const float* query_pos  = (const float*)d_in[1];
    const float* refp       = (const float*)d_in[2];
    const float* src        = (const float*)d_in[3];
    const float* w_in_intra = (const float*)d_in[4];
    const float* b_in_intra = (const float*)d_in[5];
    const float* w_out_intra= (const float*)d_in[6];
    const float* b_out_intra= (const float*)d_in[7];
    const float* g_ln_intra = (const float*)d_in[8];
    const float* b_ln_intra = (const float*)d_in[9];
    const float* w_in_inter = (const float*)d_in[10];
    const float* b_in_inter = (const float*)d_in[11];
    const float* w_out_inter= (const float*)d_in[12];
    const float* b_out_inter= (const float*)d_in[13];
    const float* g_ln_inter = (const float*)d_in[14];
    const float* b_ln_inter = (const float*)d_in[15];
    const float* off_w      = (const float*)d_in[16];
    const float* off_b      = (const float*)d_in[17];
    const float* aw_w       = (const float*)d_in[18];
    const float* aw_b       = (const float*)d_in[19];
    const float* val_w      = (const float*)d_in[20];
    const float* val_b      = (const float*)d_in[21];
    const float* co_w       = (const float*)d_in[22];
    const float* co_b       = (const float*)d_in[23];
    const float* g_ln_cross = (const float*)d_in[24];
    const float* b_ln_cross = (const float*)d_in[25];
    const float* lin1_w     = (const float*)d_in[26];
    const float* lin1_b     = (const float*)d_in[27];
    const float* lin2_w     = (const float*)d_in[28];
    const float* lin2_b     = (const float*)d_in[29];
    const float* g_ln3      = (const float*)d_in[30];
    const float* b_ln3      = (const float*)d_in[31];

    // Workspace layout (floats). Total 46,602,240 floats = 186.4 MB.
    float* ws   = (float*)d_ws;
    float* x1   = ws;             // 2,560,000   x1 / qc
    float* qkv  = ws + 2560000;   // 7,680,000   qkv intra / qkv inter
    float* attn = ws + 10240000;  // 2,560,000   attn out / sampled
    float* tgt1 = ws + 12800000;  // 2,560,000   tgt1 / offsets
    float* ti   = ws + 15360000;  // 2,560,000   ti / tgt2
    float* tmp  = ws + 17920000;  // 2,560,000   gemm epilogue scratch
    float* tA   = ws + 20480000;  // 2,560,000   inter-LN output (tgt layout)
    float* awl  = ws + 23040000;  // 1,280,000   attention-weight logits
    float* value= ws + 24320000;  // 22,282,240  value / ffn hidden
    float* out  = (float*)d_out;

    const float scale = 0.17677669529663687f;  // 1/sqrt(32)

    // ---- intra-instance self-attention (over 25 control points) ----
    add_vec4_kernel<<<2500, 256, 0, stream>>>((const float4*)tgt, (const float4*)query_pos,
                                              (float4*)x1, 640000);
    gemm_bias_kernel<<<dim3(4, 79), 256, 0, stream>>>(x1, 256, w_in_intra, 256,
                                                      b_in_intra, qkv, 768, M10K, 0);
    gemm_bias_kernel<<<dim3(2, 79), 256, 0, stream>>>(tgt, 256, w_in_intra + 512 * 256, 256,
                                                      b_in_intra + 512, qkv + 512, 768, M10K, 0);
    small_attn_kernel<<<dim3(400, 8), 64, 25 * 64 * 4, stream>>>(qkv, attn, 25, scale);
    gemm_bias_kernel<<<dim3(2, 79), 256, 0, stream>>>(attn, 256, w_out_intra, 256,
                                                      b_out_intra, tmp, 256, M10K, 0);
    add_ln_kernel<<<M10K, 64, 0, stream>>>(tgt, tmp, g_ln_intra, b_ln_intra, tgt1, 0);

    // ---- inter-instance self-attention (over 100 queries) ----
    tgt_to_ti_kernel<<<M10K, 64, 0, stream>>>(tgt1, ti);
    gemm_bias_kernel<<<dim3(6, 79), 256, 0, stream>>>(ti, 256, w_in_inter, 256,
                                                      b_in_inter, qkv, 768, M10K, 0);
    small_attn_kernel<<<dim3(100, 8), 128, 100 * 64 * 4, stream>>>(qkv, attn, 100, scale);
    gemm_bias_kernel<<<dim3(2, 79), 256, 0, stream>>>(attn, 256, w_out_inter, 256,
                                                      b_out_inter, tmp, 256, M10K, 0);
    add_ln_kernel<<<M10K, 64, 0, stream>>>(ti, tmp, g_ln_inter, b_ln_inter, tA, 1);

    // ---- deformable cross-attention ----
    add_vec4_kernel<<<2500, 256, 0, stream>>>((const float4*)tA, (const float4*)query_pos,
                                              (float4*)x1, 640000);               // qc
    gemm_bias_kernel<<<dim3(2, 680), 256, 0, stream>>>(src, 256, val_w, 256,
                                                       val_b, value, 256, MVAL, 0);
    gemm_bias_kernel<<<dim3(2, 79), 256, 0, stream>>>(x1, 256, off_w, 256,
                                                      off_b, tgt1, 256, M10K, 0);  // offsets
    gemm_bias_kernel<<<dim3(1, 79), 256, 0, stream>>>(x1, 256, aw_w, 256,
                                                      aw_b, awl, 128, M10K, 0);    // aw logits
    msdeform_sample_kernel<<<M10K, 256, 0, stream>>>(value, tgt1, awl, refp, attn);
    gemm_bias_kernel<<<dim3(2, 79), 256, 0, stream>>>(attn, 256, co_w, 256,
                                                      co_b, tmp, 256, M10K, 0);
    add_ln_kernel<<<M10K, 64, 0, stream>>>(tA, tmp, g_ln_cross, b_ln_cross, ti, 0); // ti = tgt2

    // ---- FFN ----
    gemm_bias_kernel<<<dim3(8, 79), 256, 0, stream>>>(ti, 256, lin1_w, 256,
                                                      lin1_b, value, 1024, M10K, 1); // hidden
    gemm_bias_kernel<<<dim3(2, 79), 256, 0, stream>>>(value, 1024, lin2_w, 1024,
                                                      lin2_b, tmp, 256, M10K, 0);
    add_ln_kernel<<<M10K, 64, 0, stream>>>(ti, tmp, g_ln3, b_ln3, out, 0);
}

// Round 2
// 713.216 us; speedup vs baseline: 1.6815x; 1.6815x over previous
//
#include <hip/hip_runtime.h>
#include <math.h>

// Problem constants
#define DMODEL 256
#define HEADS  8
#define HDIM   32
#define BS     4
#define NQ     100
#define NPTS   25
#define LQ     2500      // NQ*NPTS
#define M10K   10000     // BS*LQ
#define LEN_IN 21760
#define MVAL   87040     // BS*LEN_IN

typedef float f32x4 __attribute__((ext_vector_type(4)));
typedef short s16x8 __attribute__((ext_vector_type(8)));

// fp32 -> bf16 round-to-nearest-even
static __device__ __forceinline__ short f2bf(float f) {
    unsigned u = __builtin_bit_cast(unsigned, f);
    u = (u + 0x7fffu + ((u >> 16) & 1u)) >> 16;
    return (short)u;
}

// ---------------------------------------------------------------------------
// bf16-MFMA GEMM: C[M,N] = A[M,K] @ W[N,K]^T + bias[N], optional relu.
// A, W are fp32 in memory, converted to bf16 during LDS staging.
// 64x64 tile, BK=32, 256 threads (4 waves, 2x2 of 32x32 per-wave tiles,
// each wave-tile = 2x2 of 16x16x32 MFMA). N % 64 == 0, K % 32 == 0.
// ---------------------------------------------------------------------------
#define LDSK 40   // padded bf16 row stride (breaks 8-way bank conflict)

__global__ __launch_bounds__(256) void gemm_mfma_kernel(
    const float* __restrict__ A, int lda,
    const float* __restrict__ W, int K,
    const float* __restrict__ bias,
    float* __restrict__ C, int ldc,
    int M, int relu)
{
    __shared__ short As[64 * LDSK];
    __shared__ short Ws[64 * LDSK];

    const int tid = threadIdx.x;
    const int m0 = blockIdx.y * 64, n0 = blockIdx.x * 64;

    // staging assignment: thread -> (row 0..63, k-segment of 8)
    const int srow = tid >> 2;
    const int skseg = (tid & 3) * 8;

    // compute assignment
    const int wave = tid >> 6;          // 0..3
    const int wm = wave & 1, wn = wave >> 1;
    const int lane = tid & 63;
    const int lrow = lane & 15;         // row/col within 16x16
    const int kq = lane >> 4;           // 0..3

    f32x4 acc[2][2];
#pragma unroll
    for (int i = 0; i < 2; ++i)
#pragma unroll
        for (int j = 0; j < 2; ++j) acc[i][j] = (f32x4)(0.f);

    for (int k0 = 0; k0 < K; k0 += 32) {
        // ---- stage A and W tiles (fp32 -> bf16) ----
        int gm = m0 + srow;
        float4 a0 = make_float4(0.f, 0.f, 0.f, 0.f), a1 = a0;
        if (gm < M) {
            const float* ap = A + (size_t)gm * lda + k0 + skseg;
            a0 = *(const float4*)ap;
            a1 = *(const float4*)(ap + 4);
        }
        const float* wp = W + (size_t)(n0 + srow) * K + k0 + skseg;
        float4 w0 = *(const float4*)wp;
        float4 w1 = *(const float4*)(wp + 4);

        s16x8 av, wv;
        av[0] = f2bf(a0.x); av[1] = f2bf(a0.y); av[2] = f2bf(a0.z); av[3] = f2bf(a0.w);
        av[4] = f2bf(a1.x); av[5] = f2bf(a1.y); av[6] = f2bf(a1.z); av[7] = f2bf(a1.w);
        wv[0] = f2bf(w0.x); wv[1] = f2bf(w0.y); wv[2] = f2bf(w0.z); wv[3] = f2bf(w0.w);
        wv[4] = f2bf(w1.x); wv[5] = f2bf(w1.y); wv[6] = f2bf(w1.z); wv[7] = f2bf(w1.w);
        *(s16x8*)&As[srow * LDSK + skseg] = av;
        *(s16x8*)&Ws[srow * LDSK + skseg] = wv;
        __syncthreads();

        // ---- MFMA ----
        s16x8 af[2], bf[2];
#pragma unroll
        for (int i = 0; i < 2; ++i)
            af[i] = *(const s16x8*)&As[(wm * 32 + i * 16 + lrow) * LDSK + kq * 8];
#pragma unroll
        for (int j = 0; j < 2; ++j)
            bf[j] = *(const s16x8*)&Ws[(wn * 32 + j * 16 + lrow) * LDSK + kq * 8];
#pragma unroll
        for (int i = 0; i < 2; ++i)
#pragma unroll
            for (int j = 0; j < 2; ++j)
                acc[i][j] = __builtin_amdgcn_mfma_f32_16x16x32_bf16(af[i], bf[j], acc[i][j], 0, 0, 0);
        __syncthreads();
    }

    // ---- epilogue: C/D layout col=lane&15, row=kq*4+reg ----
#pragma unroll
    for (int i = 0; i < 2; ++i) {
#pragma unroll
        for (int j = 0; j < 2; ++j) {
            int col = n0 + wn * 32 + j * 16 + lrow;
            float bv = bias[col];
#pragma unroll
            for (int reg = 0; reg < 4; ++reg) {
                int gm = m0 + wm * 32 + i * 16 + kq * 4 + reg;
                if (gm < M) {
                    float v = acc[i][j][reg] + bv;
                    if (relu) v = fmaxf(v, 0.f);
                    C[(size_t)gm * ldc + col] = v;
                }
            }
        }
    }
}

// ---------------------------------------------------------------------------
// Small MHA (per (batch,head) block): flash-style online softmax, one thread
// per query row. qkv layout: [nb, S, 768] with q@0, k@256, v@512, head h at
// +h*32. Output: [nb, S, 256], head h at cols h*32.
// ---------------------------------------------------------------------------
__global__ void small_attn_kernel(const float* __restrict__ qkv,
                                  float* __restrict__ out,
                                  int S, float scale)
{
    extern __shared__ float lds[];   // [S][64]: k (32) | v (32)
    const int b = blockIdx.x, h = blockIdx.y;
    const float* base = qkv + (size_t)b * S * 768;

    for (int idx = threadIdx.x; idx < S * 64; idx += blockDim.x) {
        int r = idx >> 6, c = idx & 63;
        float v = (c < 32) ? base[r * 768 + 256 + h * 32 + c]
                           : base[r * 768 + 512 + h * 32 + (c - 32)];
        lds[idx] = v;
    }
    __syncthreads();

    const int i = threadIdx.x;
    if (i < S) {
        float q[32];
        const float* qp = base + i * 768 + h * 32;
#pragma unroll
        for (int c = 0; c < 32; ++c) q[c] = qp[c];
        float m = -1e30f, l = 0.f, acc[32];
#pragma unroll
        for (int c = 0; c < 32; ++c) acc[c] = 0.f;
        for (int j = 0; j < S; ++j) {
            const float* kj = &lds[j * 64];
            float s = 0.f;
#pragma unroll
            for (int c = 0; c < 32; ++c) s = fmaf(q[c], kj[c], s);
            s *= scale;
            float mn = fmaxf(m, s);
            float alpha = __expf(m - mn);
            float p = __expf(s - mn);
            l = l * alpha + p;
            const float* vj = kj + 32;
#pragma unroll
            for (int c = 0; c < 32; ++c) acc[c] = acc[c] * alpha + p * vj[c];
            m = mn;
        }
        float inv = 1.f / l;
        float* op = out + ((size_t)b * S + i) * 256 + h * 32;
#pragma unroll
        for (int c = 0; c < 32; ++c) op[c] = acc[c] * inv;
    }
}

// ---------------------------------------------------------------------------
// out[row] = LN(a[row] + b[row]) * g + beta.  One wave (64 threads) per row of
// 256.  transpose_mode=1: row index r is in ti layout (bp*100+q, bp=b*25+p)
// and output goes to row (b*100+q)*25+p  (transpose back to tgt layout).
// ---------------------------------------------------------------------------
__global__ __launch_bounds__(64) void add_ln_kernel(
    const float* __restrict__ a, const float* __restrict__ b,
    const float* __restrict__ g, const float* __restrict__ beta,
    float* __restrict__ out, int transpose_mode)
{
    const int r = blockIdx.x;
    const int lane = threadIdx.x;
    const float* ar = a + (size_t)r * 256;
    const float* br = b + (size_t)r * 256;
    float x[4];
    float s = 0.f;
#pragma unroll
    for (int i = 0; i < 4; ++i) {
        x[i] = ar[lane + 64 * i] + br[lane + 64 * i];
        s += x[i];
    }
#pragma unroll
    for (int off = 32; off >= 1; off >>= 1) s += __shfl_xor(s, off);
    float mean = s * (1.f / 256.f);
    float vs = 0.f;
#pragma unroll
    for (int i = 0; i < 4; ++i) { float d = x[i] - mean; vs += d * d; }
#pragma unroll
    for (int off = 32; off >= 1; off >>= 1) vs += __shfl_xor(vs, off);
    float rstd = rsqrtf(vs * (1.f / 256.f) + 1e-5f);

    size_t ro = r;
    if (transpose_mode) {
        int q = r % 100; int bp = r / 100; int p = bp % 25; int bb = bp / 25;
        ro = ((size_t)bb * 100 + q) * 25 + p;
    }
    float* orow = out + ro * 256;
#pragma unroll
    for (int i = 0; i < 4; ++i) {
        int c = lane + 64 * i;
        orow[c] = (x[i] - mean) * rstd * g[c] + beta[c];
    }
}

// ---------------------------------------------------------------------------
// elementwise o = a + b (float4)
// ---------------------------------------------------------------------------
__global__ void add_vec4_kernel(const float4* __restrict__ a,
                                const float4* __restrict__ b,
                                float4* __restrict__ o, int n4)
{
    int i = blockIdx.x * blockDim.x + threadIdx.x;
    if (i < n4) {
        float4 x = a[i], y = b[i];
        o[i] = make_float4(x.x + y.x, x.y + y.y, x.z + y.z, x.w + y.w);
    }
}

// ---------------------------------------------------------------------------
// ti[(b*25+p)*100+q][:] = tgt1[(b*100+q)*25+p][:]
// ---------------------------------------------------------------------------
__global__ __launch_bounds__(64) void tgt_to_ti_kernel(
    const float* __restrict__ tgt1, float* __restrict__ ti)
{
    const int r = blockIdx.x;              // ti row
    int q = r % 100; int bp = r / 100; int p = bp % 25; int b = bp / 25;
    const float4* srcp = (const float4*)(tgt1 + (((size_t)b * 100 + q) * 25 + p) * 256);
    float4* dstp = (float4*)(ti + (size_t)r * 256);
    dstp[threadIdx.x] = srcp[threadIdx.x];
}

// ---------------------------------------------------------------------------
// MSDeform sampling. One block per (b, lq); thread = (h = tid>>5, c = tid&31).
// value: [BS, LEN_IN, 8, 32]; off: [BS, LQ, 256]; awl: [BS, LQ, 128] (logits);
// refp: [BS, NQ, 4, 2]; out sampled: [BS, LQ, 256]  (head h at cols h*32).
// ---------------------------------------------------------------------------
__global__ __launch_bounds__(256) void msdeform_sample_kernel(
    const float* __restrict__ value,
    const float* __restrict__ off,
    const float* __restrict__ awl,
    const float* __restrict__ refp,
    float* __restrict__ sampled)
{
    const int blk = blockIdx.x;
    const int b = blk / LQ, lq = blk - b * LQ;
    const int q = lq / NPTS;
    const int h = threadIdx.x >> 5, c = threadIdx.x & 31;

    // attention-weight softmax over 16 (redundant across the 32 lanes of h)
    const float* awp = awl + ((size_t)b * LQ + lq) * 128 + h * 16;
    float w[16];
    float mx = -1e30f;
#pragma unroll
    for (int t = 0; t < 16; ++t) { w[t] = awp[t]; mx = fmaxf(mx, w[t]); }
    float sum = 0.f;
#pragma unroll
    for (int t = 0; t < 16; ++t) { w[t] = __expf(w[t] - mx); sum += w[t]; }
    const float inv = 1.f / sum;

    const float* offp = off + ((size_t)b * LQ + lq) * 256 + h * 32;
    const float* rp = refp + ((size_t)b * 100 + q) * 8;
    const float* vb = value + (size_t)b * LEN_IN * 256 + h * 32 + c;

    float acc = 0.f;
    int start = 0;
    const int sz[4] = {128, 64, 32, 16};
#pragma unroll
    for (int l = 0; l < 4; ++l) {
        const int hh = sz[l], ww = sz[l];
        const float rx = rp[l * 2 + 0], ry = rp[l * 2 + 1];
#pragma unroll
        for (int pt = 0; pt < 4; ++pt) {
            float ox = offp[(l * 4 + pt) * 2 + 0];
            float oy = offp[(l * 4 + pt) * 2 + 1];
            float x = rx * ww + ox - 0.5f;
            float y = ry * hh + oy - 0.5f;
            float x0f = floorf(x), y0f = floorf(y);
            float wx = x - x0f, wy = y - y0f;
            int x0 = (int)x0f, y0 = (int)y0f;
            int x1 = x0 + 1, y1 = y0 + 1;
            float aw = w[l * 4 + pt] * inv;

            int x0c = min(max(x0, 0), ww - 1), x1c = min(max(x1, 0), ww - 1);
            int y0c = min(max(y0, 0), hh - 1), y1c = min(max(y1, 0), hh - 1);
            float m00 = (x0 >= 0 && x0 < ww && y0 >= 0 && y0 < hh) ? 1.f : 0.f;
            float m10 = (x1 >= 0 && x1 < ww && y0 >= 0 && y0 < hh) ? 1.f : 0.f;
            float m01 = (x0 >= 0 && x0 < ww && y1 >= 0 && y1 < hh) ? 1.f : 0.f;
            float m11 = (x1 >= 0 && x1 < ww && y1 >= 0 && y1 < hh) ? 1.f : 0.f;
            float v00 = vb[(size_t)(start + y0c * ww + x0c) * 256] * m00;
            float v10 = vb[(size_t)(start + y0c * ww + x1c) * 256] * m10;
            float v01 = vb[(size_t)(start + y1c * ww + x0c) * 256] * m01;
            float v11 = vb[(size_t)(start + y1c * ww + x1c) * 256] * m11;

            acc += aw * (v00 * (1.f - wx) * (1.f - wy)
                       + v10 * wx * (1.f - wy)
                       + v01 * (1.f - wx) * wy
                       + v11 * wx * wy);
        }
        start += hh * ww;
    }
    sampled[((size_t)b * LQ + lq) * 256 + h * 32 + c] = acc;
}

// ---------------------------------------------------------------------------
extern "C" void kernel_launch(void* const* d_in, const int* in_sizes, int n_in,
                              void* d_out, int out_size, void* d_ws, size_t ws_size,
                              hipStream_t stream)
{
    (void)in_sizes; (void)n_in; (void)out_size; (void)ws_size;

    const float* tgt        = (const float*)d_in[0];
    const float* query_pos  = (const float*)d_in[1];
    const float* refp       = (const float*)d_in[2];
    const float* src        = (const float*)d_in[3];
    const float* w_in_intra = (const float*)d_in[4];
    const float* b_in_intra = (const float*)d_in[5];
    const float* w_out_intra= (const float*)d_in[6];
    const float* b_out_intra= (const float*)d_in[7];
    const float* g_ln_intra = (const float*)d_in[8];
    const float* b_ln_intra = (const float*)d_in[9];
    const float* w_in_inter = (const float*)d_in[10];
    const float* b_in_inter = (const float*)d_in[11];
    const float* w_out_inter= (const float*)d_in[12];
    const float* b_out_inter= (const float*)d_in[13];
    const float* g_ln_inter = (const float*)d_in[14];
    const float* b_ln_inter = (const float*)d_in[15];
    const float* off_w      = (const float*)d_in[16];
    const float* off_b      = (const float*)d_in[17];
    const float* aw_w       = (const float*)d_in[18];
    const float* aw_b       = (const float*)d_in[19];
    const float* val_w      = (const float*)d_in[20];
    const float* val_b      = (const float*)d_in[21];
    const float* co_w       = (const float*)d_in[22];
    const float* co_b       = (const float*)d_in[23];
    const float* g_ln_cross = (const float*)d_in[24];
    const float* b_ln_cross = (const float*)d_in[25];
    const float* lin1_w     = (const float*)d_in[26];
    const float* lin1_b     = (const float*)d_in[27];
    const float* lin2_w     = (const float*)d_in[28];
    const float* lin2_b     = (const float*)d_in[29];
    const float* g_ln3      = (const float*)d_in[30];
    const float* b_ln3      = (const float*)d_in[31];

    // Workspace layout (floats). Total 46,602,240 floats = 186.4 MB.
    float* ws   = (float*)d_ws;
    float* x1   = ws;             // 2,560,000   x1 / qc
    float* qkv  = ws + 2560000;   // 7,680,000   qkv intra / qkv inter
    float* attn = ws + 10240000;  // 2,560,000   attn out / sampled
    float* tgt1 = ws + 12800000;  // 2,560,000   tgt1 / offsets
    float* ti   = ws + 15360000;  // 2,560,000   ti / tgt2
    float* tmp  = ws + 17920000;  // 2,560,000   gemm epilogue scratch
    float* tA   = ws + 20480000;  // 2,560,000   inter-LN output (tgt layout)
    float* awl  = ws + 23040000;  // 1,280,000   attention-weight logits
    float* value= ws + 24320000;  // 22,282,240  value / ffn hidden
    float* out  = (float*)d_out;

    const float scale = 0.17677669529663687f;  // 1/sqrt(32)
    const int MB10K = (M10K + 63) / 64;        // 157

    // ---- intra-instance self-attention (over 25 control points) ----
    add_vec4_kernel<<<2500, 256, 0, stream>>>((const float4*)tgt, (const float4*)query_pos,
                                              (float4*)x1, 640000);
    gemm_mfma_kernel<<<dim3(8, MB10K), 256, 0, stream>>>(x1, 256, w_in_intra, 256,
                                                         b_in_intra, qkv, 768, M10K, 0);
    gemm_mfma_kernel<<<dim3(4, MB10K), 256, 0, stream>>>(tgt, 256, w_in_intra + 512 * 256, 256,
                                                         b_in_intra + 512, qkv + 512, 768, M10K, 0);
    small_attn_kernel<<<dim3(400, 8), 64, 25 * 64 * 4, stream>>>(qkv, attn, 25, scale);
    gemm_mfma_kernel<<<dim3(4, MB10K), 256, 0, stream>>>(attn, 256, w_out_intra, 256,
                                                         b_out_intra, tmp, 256, M10K, 0);
    add_ln_kernel<<<M10K, 64, 0, stream>>>(tgt, tmp, g_ln_intra, b_ln_intra, tgt1, 0);

    // ---- inter-instance self-attention (over 100 queries) ----
    tgt_to_ti_kernel<<<M10K, 64, 0, stream>>>(tgt1, ti);
    gemm_mfma_kernel<<<dim3(12, MB10K), 256, 0, stream>>>(ti, 256, w_in_inter, 256,
                                                          b_in_inter, qkv, 768, M10K, 0);
    small_attn_kernel<<<dim3(100, 8), 128, 100 * 64 * 4, stream>>>(qkv, attn, 100, scale);
    gemm_mfma_kernel<<<dim3(4, MB10K), 256, 0, stream>>>(attn, 256, w_out_inter, 256,
                                                         b_out_inter, tmp, 256, M10K, 0);
    add_ln_kernel<<<M10K, 64, 0, stream>>>(ti, tmp, g_ln_inter, b_ln_inter, tA, 1);

    // ---- deformable cross-attention ----
    add_vec4_kernel<<<2500, 256, 0, stream>>>((const float4*)tA, (const float4*)query_pos,
                                              (float4*)x1, 640000);               // qc
    gemm_mfma_kernel<<<dim3(4, 1360), 256, 0, stream>>>(src, 256, val_w, 256,
                                                        val_b, value, 256, MVAL, 0);
    gemm_mfma_kernel<<<dim3(4, MB10K), 256, 0, stream>>>(x1, 256, off_w, 256,
                                                         off_b, tgt1, 256, M10K, 0);  // offsets
    gemm_mfma_kernel<<<dim3(2, MB10K), 256, 0, stream>>>(x1, 256, aw_w, 256,
                                                         aw_b, awl, 128, M10K, 0);    // aw logits
    msdeform_sample_kernel<<<M10K, 256, 0, stream>>>(value, tgt1, awl, refp, attn);
    gemm_mfma_kernel<<<dim3(4, MB10K), 256, 0, stream>>>(attn, 256, co_w, 256,
                                                         co_b, tmp, 256, M10K, 0);
    add_ln_kernel<<<M10K, 64, 0, stream>>>(tA, tmp, g_ln_cross, b_ln_cross, ti, 0); // ti = tgt2

    // ---- FFN ----
    gemm_mfma_kernel<<<dim3(16, MB10K), 256, 0, stream>>>(ti, 256, lin1_w, 256,
                                                          lin1_b, value, 1024, M10K, 1); // hidden
    gemm_mfma_kernel<<<dim3(4, MB10K), 256, 0, stream>>>(value, 1024, lin2_w, 1024,
                                                         lin2_b, tmp, 256, M10K, 0);
    add_ln_kernel<<<M10K, 64, 0, stream>>>(ti, tmp, g_ln3, b_ln3, out, 0);
}

// Round 3
// 667.877 us; speedup vs baseline: 1.7957x; 1.0679x over previous
//
#include <hip/hip_runtime.h>
#include <math.h>

// Problem constants
#define DMODEL 256
#define HEADS  8
#define HDIM   32
#define BS     4
#define NQ     100
#define NPTS   25
#define LQ     2500      // NQ*NPTS
#define M10K   10000     // BS*LQ
#define LEN_IN 21760
#define MVAL   87040     // BS*LEN_IN

typedef float f32x4 __attribute__((ext_vector_type(4)));
typedef short s16x8 __attribute__((ext_vector_type(8)));
typedef unsigned short u16;

// fp32 -> bf16 round-to-nearest-even
static __device__ __forceinline__ short f2bf(float f) {
    unsigned u = __builtin_bit_cast(unsigned, f);
    u = (u + 0x7fffu + ((u >> 16) & 1u)) >> 16;
    return (short)u;
}
static __device__ __forceinline__ float bf_lo(unsigned u) {   // low 16 bits -> float
    return __builtin_bit_cast(float, u << 16);
}
static __device__ __forceinline__ float bf_hi(unsigned u) {   // high 16 bits -> float
    return __builtin_bit_cast(float, u & 0xffff0000u);
}

// ---------------------------------------------------------------------------
// bf16-MFMA GEMM: C[M,N] = (A(+A2))[M,K] @ W[N,K]^T + bias[N], optional relu.
// A, W fp32 in memory, converted to bf16 during LDS staging. A2 (optional)
// is elementwise-added to A during staging (same layout/lda).
// out_bf16: epilogue stores bf16 (C treated as u16*) instead of fp32.
// 64x64 tile, BK=32, 256 threads (2x2 waves, each 2x2 of 16x16x32 MFMA).
// ---------------------------------------------------------------------------
#define LDSK 40   // padded bf16 row stride (breaks 8-way bank conflict)

__global__ __launch_bounds__(256) void gemm_mfma_kernel(
    const float* __restrict__ A, const float* __restrict__ A2, int lda,
    const float* __restrict__ W, int K,
    const float* __restrict__ bias,
    float* __restrict__ C, int ldc,
    int M, int relu, int out_bf16)
{
    __shared__ short As[64 * LDSK];
    __shared__ short Ws[64 * LDSK];

    const int tid = threadIdx.x;
    const int m0 = blockIdx.y * 64, n0 = blockIdx.x * 64;

    const int srow = tid >> 2;
    const int skseg = (tid & 3) * 8;

    const int wave = tid >> 6;          // 0..3
    const int wm = wave & 1, wn = wave >> 1;
    const int lane = tid & 63;
    const int lrow = lane & 15;
    const int kq = lane >> 4;

    f32x4 acc[2][2];
#pragma unroll
    for (int i = 0; i < 2; ++i)
#pragma unroll
        for (int j = 0; j < 2; ++j) acc[i][j] = (f32x4)(0.f);

    for (int k0 = 0; k0 < K; k0 += 32) {
        int gm = m0 + srow;
        float4 a0 = make_float4(0.f, 0.f, 0.f, 0.f), a1 = a0;
        if (gm < M) {
            const float* ap = A + (size_t)gm * lda + k0 + skseg;
            a0 = *(const float4*)ap;
            a1 = *(const float4*)(ap + 4);
            if (A2) {
                const float* ap2 = A2 + (size_t)gm * lda + k0 + skseg;
                float4 b0 = *(const float4*)ap2;
                float4 b1 = *(const float4*)(ap2 + 4);
                a0.x += b0.x; a0.y += b0.y; a0.z += b0.z; a0.w += b0.w;
                a1.x += b1.x; a1.y += b1.y; a1.z += b1.z; a1.w += b1.w;
            }
        }
        const float* wp = W + (size_t)(n0 + srow) * K + k0 + skseg;
        float4 w0 = *(const float4*)wp;
        float4 w1 = *(const float4*)(wp + 4);

        s16x8 av, wv;
        av[0] = f2bf(a0.x); av[1] = f2bf(a0.y); av[2] = f2bf(a0.z); av[3] = f2bf(a0.w);
        av[4] = f2bf(a1.x); av[5] = f2bf(a1.y); av[6] = f2bf(a1.z); av[7] = f2bf(a1.w);
        wv[0] = f2bf(w0.x); wv[1] = f2bf(w0.y); wv[2] = f2bf(w0.z); wv[3] = f2bf(w0.w);
        wv[4] = f2bf(w1.x); wv[5] = f2bf(w1.y); wv[6] = f2bf(w1.z); wv[7] = f2bf(w1.w);
        *(s16x8*)&As[srow * LDSK + skseg] = av;
        *(s16x8*)&Ws[srow * LDSK + skseg] = wv;
        __syncthreads();

        s16x8 af[2], bf[2];
#pragma unroll
        for (int i = 0; i < 2; ++i)
            af[i] = *(const s16x8*)&As[(wm * 32 + i * 16 + lrow) * LDSK + kq * 8];
#pragma unroll
        for (int j = 0; j < 2; ++j)
            bf[j] = *(const s16x8*)&Ws[(wn * 32 + j * 16 + lrow) * LDSK + kq * 8];
#pragma unroll
        for (int i = 0; i < 2; ++i)
#pragma unroll
            for (int j = 0; j < 2; ++j)
                acc[i][j] = __builtin_amdgcn_mfma_f32_16x16x32_bf16(af[i], bf[j], acc[i][j], 0, 0, 0);
        __syncthreads();
    }

    // epilogue: C/D layout col=lane&15, row=kq*4+reg
#pragma unroll
    for (int i = 0; i < 2; ++i) {
#pragma unroll
        for (int j = 0; j < 2; ++j) {
            int col = n0 + wn * 32 + j * 16 + lrow;
            float bv = bias[col];
#pragma unroll
            for (int reg = 0; reg < 4; ++reg) {
                int gm = m0 + wm * 32 + i * 16 + kq * 4 + reg;
                if (gm < M) {
                    float v = acc[i][j][reg] + bv;
                    if (relu) v = fmaxf(v, 0.f);
                    if (out_bf16)
                        ((u16*)C)[(size_t)gm * ldc + col] = (u16)f2bf(v);
                    else
                        C[(size_t)gm * ldc + col] = v;
                }
            }
        }
    }
}

// ---------------------------------------------------------------------------
// Small MHA (per (batch,head) block): flash-style online softmax, one thread
// per query row. qkv layout: [nb, S, 768] with q@0, k@256, v@512, head h at
// +h*32. Output: [nb, S, 256], head h at cols h*32.
// ---------------------------------------------------------------------------
__global__ void small_attn_kernel(const float* __restrict__ qkv,
                                  float* __restrict__ out,
                                  int S, float scale)
{
    extern __shared__ float lds[];   // [S][64]: k (32) | v (32)
    const int b = blockIdx.x, h = blockIdx.y;
    const float* base = qkv + (size_t)b * S * 768;

    for (int idx = threadIdx.x; idx < S * 64; idx += blockDim.x) {
        int r = idx >> 6, c = idx & 63;
        float v = (c < 32) ? base[r * 768 + 256 + h * 32 + c]
                           : base[r * 768 + 512 + h * 32 + (c - 32)];
        lds[idx] = v;
    }
    __syncthreads();

    const int i = threadIdx.x;
    if (i < S) {
        float q[32];
        const float* qp = base + i * 768 + h * 32;
#pragma unroll
        for (int c = 0; c < 32; ++c) q[c] = qp[c];
        float m = -1e30f, l = 0.f, acc[32];
#pragma unroll
        for (int c = 0; c < 32; ++c) acc[c] = 0.f;
        for (int j = 0; j < S; ++j) {
            const float* kj = &lds[j * 64];
            float s = 0.f;
#pragma unroll
            for (int c = 0; c < 32; ++c) s = fmaf(q[c], kj[c], s);
            s *= scale;
            float mn = fmaxf(m, s);
            float alpha = __expf(m - mn);
            float p = __expf(s - mn);
            l = l * alpha + p;
            const float* vj = kj + 32;
#pragma unroll
            for (int c = 0; c < 32; ++c) acc[c] = acc[c] * alpha + p * vj[c];
            m = mn;
        }
        float inv = 1.f / l;
        float* op = out + ((size_t)b * S + i) * 256 + h * 32;
#pragma unroll
        for (int c = 0; c < 32; ++c) op[c] = acc[c] * inv;
    }
}

// ---------------------------------------------------------------------------
// out[row] = LN(a[row] + b[row]) * g + beta.  One wave per row of 256.
// ---------------------------------------------------------------------------
__global__ __launch_bounds__(64) void add_ln_kernel(
    const float* __restrict__ a, const float* __restrict__ b,
    const float* __restrict__ g, const float* __restrict__ beta,
    float* __restrict__ out, int transpose_mode)
{
    const int r = blockIdx.x;
    const int lane = threadIdx.x;
    const float* ar = a + (size_t)r * 256;
    const float* br = b + (size_t)r * 256;
    float x[4];
    float s = 0.f;
#pragma unroll
    for (int i = 0; i < 4; ++i) {
        x[i] = ar[lane + 64 * i] + br[lane + 64 * i];
        s += x[i];
    }
#pragma unroll
    for (int off = 32; off >= 1; off >>= 1) s += __shfl_xor(s, off);
    float mean = s * (1.f / 256.f);
    float vs = 0.f;
#pragma unroll
    for (int i = 0; i < 4; ++i) { float d = x[i] - mean; vs += d * d; }
#pragma unroll
    for (int off = 32; off >= 1; off >>= 1) vs += __shfl_xor(vs, off);
    float rstd = rsqrtf(vs * (1.f / 256.f) + 1e-5f);

    size_t ro = r;
    if (transpose_mode) {
        int q = r % 100; int bp = r / 100; int p = bp % 25; int bb = bp / 25;
        ro = ((size_t)bb * 100 + q) * 25 + p;
    }
    float* orow = out + ro * 256;
#pragma unroll
    for (int i = 0; i < 4; ++i) {
        int c = lane + 64 * i;
        orow[c] = (x[i] - mean) * rstd * g[c] + beta[c];
    }
}

// ---------------------------------------------------------------------------
// ti[(b*25+p)*100+q][:] = tgt1[(b*100+q)*25+p][:]
// ---------------------------------------------------------------------------
__global__ __launch_bounds__(64) void tgt_to_ti_kernel(
    const float* __restrict__ tgt1, float* __restrict__ ti)
{
    const int r = blockIdx.x;              // ti row
    int q = r % 100; int bp = r / 100; int p = bp % 25; int b = bp / 25;
    const float4* srcp = (const float4*)(tgt1 + (((size_t)b * 100 + q) * 25 + p) * 256);
    float4* dstp = (float4*)(ti + (size_t)r * 256);
    dstp[threadIdx.x] = srcp[threadIdx.x];
}

// ---------------------------------------------------------------------------
// MSDeform sampling, bf16 value, 8 channels/thread.
// Block = 256 threads = 8 query-units. Within a unit's 32 threads:
// h = (t>>2), c8 = (t&3) -> channels c8*8 .. c8*8+7.
// value: bf16 [BS, LEN_IN, 8, 32]; off: fp32 [M10K, 256]; awl: [M10K, 128];
// refp: [BS, NQ, 4, 2]; sampled: fp32 [M10K, 256].
// ---------------------------------------------------------------------------
__global__ __launch_bounds__(256) void msdeform_sample_kernel(
    const u16* __restrict__ value,
    const float* __restrict__ off,
    const float* __restrict__ awl,
    const float* __restrict__ refp,
    float* __restrict__ sampled)
{
    const int unit = blockIdx.x * 8 + (threadIdx.x >> 5);
    const int t = threadIdx.x & 31;
    const int h = t >> 2, c8 = t & 3;
    const int b = unit / LQ, lq = unit - b * LQ;
    const int q = lq / NPTS;

    // softmax over this head's 16 logits (4x lane-redundant)
    const float* awp = awl + (size_t)unit * 128 + h * 16;
    float w[16];
    float mx = -1e30f;
#pragma unroll
    for (int k = 0; k < 16; ++k) { w[k] = awp[k]; mx = fmaxf(mx, w[k]); }
    float sum = 0.f;
#pragma unroll
    for (int k = 0; k < 16; ++k) { w[k] = __expf(w[k] - mx); sum += w[k]; }
    const float inv = 1.f / sum;

    const float* offp = off + (size_t)unit * 256 + h * 32;
    const float* rp = refp + ((size_t)b * 100 + q) * 8;
    const u16* vbase = value + (size_t)b * LEN_IN * 256 + h * 32 + c8 * 8;

    float acc[8];
#pragma unroll
    for (int k = 0; k < 8; ++k) acc[k] = 0.f;

    int start = 0;
    const int sz[4] = {128, 64, 32, 16};
#pragma unroll
    for (int l = 0; l < 4; ++l) {
        const int hh = sz[l], ww = sz[l];
        const float rx = rp[l * 2 + 0], ry = rp[l * 2 + 1];
#pragma unroll
        for (int pt = 0; pt < 4; ++pt) {
            float ox = offp[(l * 4 + pt) * 2 + 0];
            float oy = offp[(l * 4 + pt) * 2 + 1];
            float x = rx * ww + ox - 0.5f;
            float y = ry * hh + oy - 0.5f;
            float x0f = floorf(x), y0f = floorf(y);
            float wx = x - x0f, wy = y - y0f;
            int x0 = (int)x0f, y0 = (int)y0f;
            int x1 = x0 + 1, y1 = y0 + 1;
            float aw = w[l * 4 + pt] * inv;

            int x0c = min(max(x0, 0), ww - 1), x1c = min(max(x1, 0), ww - 1);
            int y0c = min(max(y0, 0), hh - 1), y1c = min(max(y1, 0), hh - 1);
            float w00 = aw * (1.f - wx) * (1.f - wy);
            float w10 = aw * wx * (1.f - wy);
            float w01 = aw * (1.f - wx) * wy;
            float w11 = aw * wx * wy;
            if (!(x0 >= 0 && x0 < ww)) { w00 = 0.f; w01 = 0.f; }
            if (!(x1 >= 0 && x1 < ww)) { w10 = 0.f; w11 = 0.f; }
            if (!(y0 >= 0 && y0 < hh)) { w00 = 0.f; w10 = 0.f; }
            if (!(y1 >= 0 && y1 < hh)) { w01 = 0.f; w11 = 0.f; }

            uint4 u00 = *(const uint4*)(vbase + (size_t)(start + y0c * ww + x0c) * 256);
            uint4 u10 = *(const uint4*)(vbase + (size_t)(start + y0c * ww + x1c) * 256);
            uint4 u01 = *(const uint4*)(vbase + (size_t)(start + y1c * ww + x0c) * 256);
            uint4 u11 = *(const uint4*)(vbase + (size_t)(start + y1c * ww + x1c) * 256);

#define ACC4(u, wgt) \
            acc[0] = fmaf(wgt, bf_lo(u.x), acc[0]); \
            acc[1] = fmaf(wgt, bf_hi(u.x), acc[1]); \
            acc[2] = fmaf(wgt, bf_lo(u.y), acc[2]); \
            acc[3] = fmaf(wgt, bf_hi(u.y), acc[3]); \
            acc[4] = fmaf(wgt, bf_lo(u.z), acc[4]); \
            acc[5] = fmaf(wgt, bf_hi(u.z), acc[5]); \
            acc[6] = fmaf(wgt, bf_lo(u.w), acc[6]); \
            acc[7] = fmaf(wgt, bf_hi(u.w), acc[7]);
            ACC4(u00, w00); ACC4(u10, w10); ACC4(u01, w01); ACC4(u11, w11);
#undef ACC4
        }
        start += hh * ww;
    }

    float* op = sampled + (size_t)unit * 256 + h * 32 + c8 * 8;
    *(float4*)op       = make_float4(acc[0], acc[1], acc[2], acc[3]);
    *(float4*)(op + 4) = make_float4(acc[4], acc[5], acc[6], acc[7]);
}

// ---------------------------------------------------------------------------
extern "C" void kernel_launch(void* const* d_in, const int* in_sizes, int n_in,
                              void* d_out, int out_size, void* d_ws, size_t ws_size,
                              hipStream_t stream)
{
    (void)in_sizes; (void)n_in; (void)out_size; (void)ws_size;

    const float* tgt        = (const float*)d_in[0];
    const float* query_pos  = (const float*)d_in[1];
    const float* refp       = (const float*)d_in[2];
    const float* src        = (const float*)d_in[3];
    const float* w_in_intra = (const float*)d_in[4];
    const float* b_in_intra = (const float*)d_in[5];
    const float* w_out_intra= (const float*)d_in[6];
    const float* b_out_intra= (const float*)d_in[7];
    const float* g_ln_intra = (const float*)d_in[8];
    const float* b_ln_intra = (const float*)d_in[9];
    const float* w_in_inter = (const float*)d_in[10];
    const float* b_in_inter = (const float*)d_in[11];
    const float* w_out_inter= (const float*)d_in[12];
    const float* b_out_inter= (const float*)d_in[13];
    const float* g_ln_inter = (const float*)d_in[14];
    const float* b_ln_inter = (const float*)d_in[15];
    const float* off_w      = (const float*)d_in[16];
    const float* off_b      = (const float*)d_in[17];
    const float* aw_w       = (const float*)d_in[18];
    const float* aw_b       = (const float*)d_in[19];
    const float* val_w      = (const float*)d_in[20];
    const float* val_b      = (const float*)d_in[21];
    const float* co_w       = (const float*)d_in[22];
    const float* co_b       = (const float*)d_in[23];
    const float* g_ln_cross = (const float*)d_in[24];
    const float* b_ln_cross = (const float*)d_in[25];
    const float* lin1_w     = (const float*)d_in[26];
    const float* lin1_b     = (const float*)d_in[27];
    const float* lin2_w     = (const float*)d_in[28];
    const float* lin2_b     = (const float*)d_in[29];
    const float* g_ln3      = (const float*)d_in[30];
    const float* b_ln3      = (const float*)d_in[31];

    // Workspace layout (floats). Total 46,602,240 floats = 186.4 MB.
    float* ws   = (float*)d_ws;
    float* qkv  = ws + 2560000;   // 7,680,000   qkv intra / qkv inter
    float* attn = ws + 10240000;  // 2,560,000   attn out / sampled
    float* tgt1 = ws + 12800000;  // 2,560,000   tgt1 / offsets
    float* ti   = ws + 15360000;  // 2,560,000   ti / tgt2
    float* tmp  = ws + 17920000;  // 2,560,000   gemm epilogue scratch
    float* tA   = ws + 20480000;  // 2,560,000   inter-LN output (tgt layout)
    float* awl  = ws + 23040000;  // 1,280,000   attention-weight logits
    float* value= ws + 24320000;  // 22,282,240  value(bf16) / ffn hidden(fp32)
    float* out  = (float*)d_out;

    const float scale = 0.17677669529663687f;  // 1/sqrt(32)
    const int MB10K = (M10K + 63) / 64;        // 157

    // ---- intra-instance self-attention (over 25 control points) ----
    gemm_mfma_kernel<<<dim3(8, MB10K), 256, 0, stream>>>(tgt, query_pos, 256, w_in_intra, 256,
                                                         b_in_intra, qkv, 768, M10K, 0, 0);
    gemm_mfma_kernel<<<dim3(4, MB10K), 256, 0, stream>>>(tgt, nullptr, 256, w_in_intra + 512 * 256, 256,
                                                         b_in_intra + 512, qkv + 512, 768, M10K, 0, 0);
    small_attn_kernel<<<dim3(400, 8), 64, 25 * 64 * 4, stream>>>(qkv, attn, 25, scale);
    gemm_mfma_kernel<<<dim3(4, MB10K), 256, 0, stream>>>(attn, nullptr, 256, w_out_intra, 256,
                                                         b_out_intra, tmp, 256, M10K, 0, 0);
    add_ln_kernel<<<M10K, 64, 0, stream>>>(tgt, tmp, g_ln_intra, b_ln_intra, tgt1, 0);

    // ---- inter-instance self-attention (over 100 queries) ----
    tgt_to_ti_kernel<<<M10K, 64, 0, stream>>>(tgt1, ti);
    gemm_mfma_kernel<<<dim3(12, MB10K), 256, 0, stream>>>(ti, nullptr, 256, w_in_inter, 256,
                                                          b_in_inter, qkv, 768, M10K, 0, 0);
    small_attn_kernel<<<dim3(100, 8), 128, 100 * 64 * 4, stream>>>(qkv, attn, 100, scale);
    gemm_mfma_kernel<<<dim3(4, MB10K), 256, 0, stream>>>(attn, nullptr, 256, w_out_inter, 256,
                                                         b_out_inter, tmp, 256, M10K, 0, 0);
    add_ln_kernel<<<M10K, 64, 0, stream>>>(ti, tmp, g_ln_inter, b_ln_inter, tA, 1);

    // ---- deformable cross-attention ----
    gemm_mfma_kernel<<<dim3(4, 1360), 256, 0, stream>>>(src, nullptr, 256, val_w, 256,
                                                        val_b, value, 256, MVAL, 0, 1);  // bf16 out
    gemm_mfma_kernel<<<dim3(4, MB10K), 256, 0, stream>>>(tA, query_pos, 256, off_w, 256,
                                                         off_b, tgt1, 256, M10K, 0, 0);  // offsets
    gemm_mfma_kernel<<<dim3(2, MB10K), 256, 0, stream>>>(tA, query_pos, 256, aw_w, 256,
                                                         aw_b, awl, 128, M10K, 0, 0);    // aw logits
    msdeform_sample_kernel<<<1250, 256, 0, stream>>>((const u16*)value, tgt1, awl, refp, attn);
    gemm_mfma_kernel<<<dim3(4, MB10K), 256, 0, stream>>>(attn, nullptr, 256, co_w, 256,
                                                         co_b, tmp, 256, M10K, 0, 0);
    add_ln_kernel<<<M10K, 64, 0, stream>>>(tA, tmp, g_ln_cross, b_ln_cross, ti, 0); // ti = tgt2

    // ---- FFN ----
    gemm_mfma_kernel<<<dim3(16, MB10K), 256, 0, stream>>>(ti, nullptr, 256, lin1_w, 256,
                                                          lin1_b, value, 1024, M10K, 1, 0); // hidden
    gemm_mfma_kernel<<<dim3(4, MB10K), 256, 0, stream>>>(value, nullptr, 1024, lin2_w, 1024,
                                                         lin2_b, tmp, 256, M10K, 0, 0);
    add_ln_kernel<<<M10K, 64, 0, stream>>>(ti, tmp, g_ln3, b_ln3, out, 0);
}

// Round 4
// 562.370 us; speedup vs baseline: 2.1326x; 1.1876x over previous
//
#include <hip/hip_runtime.h>
#include <math.h>

// Problem constants
#define DMODEL 256
#define HEADS  8
#define HDIM   32
#define BS     4
#define NQ     100
#define NPTS   25
#define LQ     2500      // NQ*NPTS
#define M10K   10000     // BS*LQ
#define LEN_IN 21760
#define MVAL   87040     // BS*LEN_IN

typedef float f32x4 __attribute__((ext_vector_type(4)));
typedef short s16x8 __attribute__((ext_vector_type(8)));
typedef unsigned short u16;

// fp32 -> bf16 round-to-nearest-even
static __device__ __forceinline__ short f2bf(float f) {
    unsigned u = __builtin_bit_cast(unsigned, f);
    u = (u + 0x7fffu + ((u >> 16) & 1u)) >> 16;
    return (short)u;
}
static __device__ __forceinline__ unsigned pack2(float lo, float hi) {
    return (unsigned)(u16)f2bf(lo) | ((unsigned)(u16)f2bf(hi) << 16);
}
static __device__ __forceinline__ float bf_lo(unsigned u) {
    return __builtin_bit_cast(float, u << 16);
}
static __device__ __forceinline__ float bf_hi(unsigned u) {
    return __builtin_bit_cast(float, u & 0xffff0000u);
}

// ---------------------------------------------------------------------------
// One-shot weight conversion: 10 fp32 weight matrices -> concatenated bf16.
// 8 elements/thread; all segment boundaries are multiples of 8.
// ---------------------------------------------------------------------------
__global__ __launch_bounds__(256) void convert_weights_kernel(
    const float* __restrict__ s0, const float* __restrict__ s1,
    const float* __restrict__ s2, const float* __restrict__ s3,
    const float* __restrict__ s4, const float* __restrict__ s5,
    const float* __restrict__ s6, const float* __restrict__ s7,
    const float* __restrict__ s8, const float* __restrict__ s9,
    u16* __restrict__ dst)
{
    int t8 = (blockIdx.x * 256 + threadIdx.x) * 8;
    if (t8 >= 1277952) return;
    const float* s; int base;
    if      (t8 <  196608) { s = s0; base = 0;       }
    else if (t8 <  262144) { s = s1; base = 196608;  }
    else if (t8 <  458752) { s = s2; base = 262144;  }
    else if (t8 <  524288) { s = s3; base = 458752;  }
    else if (t8 <  589824) { s = s4; base = 524288;  }
    else if (t8 <  622592) { s = s5; base = 589824;  }
    else if (t8 <  688128) { s = s6; base = 622592;  }
    else if (t8 <  753664) { s = s7; base = 688128;  }
    else if (t8 < 1015808) { s = s8; base = 753664;  }
    else                   { s = s9; base = 1015808; }
    const float* p = s + (t8 - base);
    float4 a = *(const float4*)p;
    float4 b = *(const float4*)(p + 4);
    s16x8 v;
    v[0]=f2bf(a.x); v[1]=f2bf(a.y); v[2]=f2bf(a.z); v[3]=f2bf(a.w);
    v[4]=f2bf(b.x); v[5]=f2bf(b.y); v[6]=f2bf(b.z); v[7]=f2bf(b.w);
    *(s16x8*)(dst + t8) = v;
}

// ---------------------------------------------------------------------------
// xb = bf16(a + b) (b optional); ab = bf16(a) (optional). 8 elems/thread.
// ---------------------------------------------------------------------------
__global__ __launch_bounds__(256) void add_convert_kernel(
    const float* __restrict__ a, const float* __restrict__ b,
    u16* __restrict__ xb, u16* __restrict__ ab, int n8)
{
    int i = blockIdx.x * 256 + threadIdx.x;
    if (i >= n8) return;
    size_t o = (size_t)i * 8;
    float4 a0 = *(const float4*)(a + o);
    float4 a1 = *(const float4*)(a + o + 4);
    if (ab) {
        s16x8 v;
        v[0]=f2bf(a0.x); v[1]=f2bf(a0.y); v[2]=f2bf(a0.z); v[3]=f2bf(a0.w);
        v[4]=f2bf(a1.x); v[5]=f2bf(a1.y); v[6]=f2bf(a1.z); v[7]=f2bf(a1.w);
        *(s16x8*)(ab + o) = v;
    }
    if (b) {
        float4 b0 = *(const float4*)(b + o);
        float4 b1 = *(const float4*)(b + o + 4);
        a0.x += b0.x; a0.y += b0.y; a0.z += b0.z; a0.w += b0.w;
        a1.x += b1.x; a1.y += b1.y; a1.z += b1.z; a1.w += b1.w;
    }
    s16x8 v;
    v[0]=f2bf(a0.x); v[1]=f2bf(a0.y); v[2]=f2bf(a0.z); v[3]=f2bf(a0.w);
    v[4]=f2bf(a1.x); v[5]=f2bf(a1.y); v[6]=f2bf(a1.z); v[7]=f2bf(a1.w);
    *(s16x8*)(xb + o) = v;
}

// ---------------------------------------------------------------------------
// bf16-MFMA GEMM: C[M,N] = A[M,K] @ W[N,K]^T + bias[N].
// W is bf16 (pre-converted). A is bf16 if a_bf16 else fp32 (converted in
// staging). out_bf16: store bf16. 64x64 tile, BK=32, 256 threads.
// ---------------------------------------------------------------------------
#define LDSK 40   // padded bf16 row stride (zero bank conflicts, measured)

__global__ __launch_bounds__(256) void gemm_mfma_kernel(
    const void* __restrict__ Av, int a_bf16, int lda,
    const u16* __restrict__ W, int K,
    const float* __restrict__ bias,
    void* __restrict__ Cv, int ldc,
    int M, int relu, int out_bf16)
{
    __shared__ short As[64 * LDSK];
    __shared__ short Ws[64 * LDSK];

    const int tid = threadIdx.x;
    const int m0 = blockIdx.y * 64, n0 = blockIdx.x * 64;

    const int srow = tid >> 2;
    const int skseg = (tid & 3) * 8;

    const int wave = tid >> 6;
    const int wm = wave & 1, wn = wave >> 1;
    const int lane = tid & 63;
    const int lrow = lane & 15;
    const int kq = lane >> 4;

    f32x4 acc[2][2];
#pragma unroll
    for (int i = 0; i < 2; ++i)
#pragma unroll
        for (int j = 0; j < 2; ++j) acc[i][j] = (f32x4)(0.f);

    for (int k0 = 0; k0 < K; k0 += 32) {
        int gm = m0 + srow;
        s16x8 av = (s16x8)0;
        if (a_bf16) {
            if (gm < M)
                av = *(const s16x8*)((const u16*)Av + (size_t)gm * lda + k0 + skseg);
        } else {
            if (gm < M) {
                const float* ap = (const float*)Av + (size_t)gm * lda + k0 + skseg;
                float4 a0 = *(const float4*)ap;
                float4 a1 = *(const float4*)(ap + 4);
                av[0]=f2bf(a0.x); av[1]=f2bf(a0.y); av[2]=f2bf(a0.z); av[3]=f2bf(a0.w);
                av[4]=f2bf(a1.x); av[5]=f2bf(a1.y); av[6]=f2bf(a1.z); av[7]=f2bf(a1.w);
            }
        }
        s16x8 wv = *(const s16x8*)(W + (size_t)(n0 + srow) * K + k0 + skseg);
        *(s16x8*)&As[srow * LDSK + skseg] = av;
        *(s16x8*)&Ws[srow * LDSK + skseg] = wv;
        __syncthreads();

        s16x8 af[2], bf[2];
#pragma unroll
        for (int i = 0; i < 2; ++i)
            af[i] = *(const s16x8*)&As[(wm * 32 + i * 16 + lrow) * LDSK + kq * 8];
#pragma unroll
        for (int j = 0; j < 2; ++j)
            bf[j] = *(const s16x8*)&Ws[(wn * 32 + j * 16 + lrow) * LDSK + kq * 8];
#pragma unroll
        for (int i = 0; i < 2; ++i)
#pragma unroll
            for (int j = 0; j < 2; ++j)
                acc[i][j] = __builtin_amdgcn_mfma_f32_16x16x32_bf16(af[i], bf[j], acc[i][j], 0, 0, 0);
        __syncthreads();
    }

    // epilogue: C/D layout col=lane&15, row=kq*4+reg
#pragma unroll
    for (int i = 0; i < 2; ++i) {
#pragma unroll
        for (int j = 0; j < 2; ++j) {
            int col = n0 + wn * 32 + j * 16 + lrow;
            float bv = bias[col];
#pragma unroll
            for (int reg = 0; reg < 4; ++reg) {
                int gm = m0 + wm * 32 + i * 16 + kq * 4 + reg;
                if (gm < M) {
                    float v = acc[i][j][reg] + bv;
                    if (relu) v = fmaxf(v, 0.f);
                    if (out_bf16)
                        ((u16*)Cv)[(size_t)gm * ldc + col] = (u16)f2bf(v);
                    else
                        ((float*)Cv)[(size_t)gm * ldc + col] = v;
                }
            }
        }
    }
}

// ---------------------------------------------------------------------------
// Small MHA: one thread per query row, K/V staged in LDS. Output bf16.
// qkv: fp32 [nb, S, 768] (q@0,k@256,v@512, head h at +h*32).
// out: bf16 [nb, S, 256].
// ---------------------------------------------------------------------------
__global__ void small_attn_kernel(const float* __restrict__ qkv,
                                  u16* __restrict__ out,
                                  int S, float scale)
{
    extern __shared__ float lds[];   // [S][64]: k (32) | v (32)
    const int b = blockIdx.x, h = blockIdx.y;
    const float* base = qkv + (size_t)b * S * 768;

    for (int idx = threadIdx.x; idx < S * 64; idx += blockDim.x) {
        int r = idx >> 6, c = idx & 63;
        float v = (c < 32) ? base[r * 768 + 256 + h * 32 + c]
                           : base[r * 768 + 512 + h * 32 + (c - 32)];
        lds[idx] = v;
    }
    __syncthreads();

    const int i = threadIdx.x;
    if (i < S) {
        float q[32];
        const float* qp = base + i * 768 + h * 32;
#pragma unroll
        for (int c = 0; c < 32; ++c) q[c] = qp[c];
        float m = -1e30f, l = 0.f, acc[32];
#pragma unroll
        for (int c = 0; c < 32; ++c) acc[c] = 0.f;
        for (int j = 0; j < S; ++j) {
            const float* kj = &lds[j * 64];
            float s = 0.f;
#pragma unroll
            for (int c = 0; c < 32; ++c) s = fmaf(q[c], kj[c], s);
            s *= scale;
            float mn = fmaxf(m, s);
            float alpha = __expf(m - mn);
            float p = __expf(s - mn);
            l = l * alpha + p;
            const float* vj = kj + 32;
#pragma unroll
            for (int c = 0; c < 32; ++c) acc[c] = acc[c] * alpha + p * vj[c];
            m = mn;
        }
        float inv = 1.f / l;
        unsigned* op = (unsigned*)(out + ((size_t)b * S + i) * 256 + h * 32);
#pragma unroll
        for (int c = 0; c < 16; ++c)
            op[c] = pack2(acc[2 * c] * inv, acc[2 * c + 1] * inv);
    }
}

// ---------------------------------------------------------------------------
// out[row] = LN(a[row] + b[row]) * g + beta; optional bf16 mirror out_bf.
// ---------------------------------------------------------------------------
__global__ __launch_bounds__(64) void add_ln_kernel(
    const float* __restrict__ a, const float* __restrict__ b,
    const float* __restrict__ g, const float* __restrict__ beta,
    float* __restrict__ out, u16* __restrict__ out_bf, int transpose_mode)
{
    const int r = blockIdx.x;
    const int lane = threadIdx.x;
    const float* ar = a + (size_t)r * 256;
    const float* br = b + (size_t)r * 256;
    float x[4];
    float s = 0.f;
#pragma unroll
    for (int i = 0; i < 4; ++i) {
        x[i] = ar[lane + 64 * i] + br[lane + 64 * i];
        s += x[i];
    }
#pragma unroll
    for (int off = 32; off >= 1; off >>= 1) s += __shfl_xor(s, off);
    float mean = s * (1.f / 256.f);
    float vs = 0.f;
#pragma unroll
    for (int i = 0; i < 4; ++i) { float d = x[i] - mean; vs += d * d; }
#pragma unroll
    for (int off = 32; off >= 1; off >>= 1) vs += __shfl_xor(vs, off);
    float rstd = rsqrtf(vs * (1.f / 256.f) + 1e-5f);

    size_t ro = r;
    if (transpose_mode) {
        int q = r % 100; int bp = r / 100; int p = bp % 25; int bb = bp / 25;
        ro = ((size_t)bb * 100 + q) * 25 + p;
    }
    float* orow = out + ro * 256;
    u16* brow = out_bf ? out_bf + ro * 256 : (u16*)0;
#pragma unroll
    for (int i = 0; i < 4; ++i) {
        int c = lane + 64 * i;
        float v = (x[i] - mean) * rstd * g[c] + beta[c];
        orow[c] = v;
        if (brow) brow[c] = (u16)f2bf(v);
    }
}

// ---------------------------------------------------------------------------
// ti[(b*25+p)*100+q][:] = tgt1[(b*100+q)*25+p][:]  (fp32 + bf16 mirror)
// ---------------------------------------------------------------------------
__global__ __launch_bounds__(64) void tgt_to_ti_kernel(
    const float* __restrict__ tgt1, float* __restrict__ ti, u16* __restrict__ tib)
{
    const int r = blockIdx.x;              // ti row
    int q = r % 100; int bp = r / 100; int p = bp % 25; int b = bp / 25;
    const float4* srcp = (const float4*)(tgt1 + (((size_t)b * 100 + q) * 25 + p) * 256);
    float4 v = srcp[threadIdx.x];
    ((float4*)(ti + (size_t)r * 256))[threadIdx.x] = v;
    uint2 pk = make_uint2(pack2(v.x, v.y), pack2(v.z, v.w));
    ((uint2*)(tib + (size_t)r * 256))[threadIdx.x] = pk;
}

// ---------------------------------------------------------------------------
// MSDeform sampling, bf16 value, 8 channels/thread, bf16 output.
// Point loop NOT unrolled (round-3 full unroll spilled: VGPR=256, 102 MB
// scratch writes). 4 corner loads in flight per iter; occupancy hides latency.
// ---------------------------------------------------------------------------
__global__ __launch_bounds__(256, 4) void msdeform_sample_kernel(
    const u16* __restrict__ value,
    const float* __restrict__ off,
    const float* __restrict__ awl,
    const float* __restrict__ refp,
    u16* __restrict__ sampled)
{
    const int unit = blockIdx.x * 8 + (threadIdx.x >> 5);
    const int t = threadIdx.x & 31;
    const int h = t >> 2, c8 = t & 3;
    const int b = unit / LQ, lq = unit - b * LQ;
    const int q = lq / NPTS;

    // softmax over this head's 16 logits (4x lane-redundant)
    const float* awp = awl + (size_t)unit * 128 + h * 16;
    float w[16];
    float mx = -1e30f;
#pragma unroll
    for (int k = 0; k < 16; ++k) { w[k] = awp[k]; mx = fmaxf(mx, w[k]); }
    float sum = 0.f;
#pragma unroll
    for (int k = 0; k < 16; ++k) { w[k] = __expf(w[k] - mx); sum += w[k]; }
    const float inv = 1.f / sum;

    const float* offp = off + (size_t)unit * 256 + h * 32;
    const float* rp = refp + ((size_t)b * 100 + q) * 8;
    const u16* vbase = value + (size_t)b * LEN_IN * 256 + h * 32 + c8 * 8;

    float acc[8];
#pragma unroll
    for (int k = 0; k < 8; ++k) acc[k] = 0.f;

    int start = 0;
    const int sz[4] = {128, 64, 32, 16};
#pragma unroll
    for (int l = 0; l < 4; ++l) {
        const int hh = sz[l], ww = sz[l];
        const float rx = rp[l * 2 + 0], ry = rp[l * 2 + 1];
#pragma unroll 1
        for (int pt = 0; pt < 4; ++pt) {
            float ox = offp[(l * 4 + pt) * 2 + 0];
            float oy = offp[(l * 4 + pt) * 2 + 1];
            float x = rx * ww + ox - 0.5f;
            float y = ry * hh + oy - 0.5f;
            float x0f = floorf(x), y0f = floorf(y);
            float wx = x - x0f, wy = y - y0f;
            int x0 = (int)x0f, y0 = (int)y0f;
            int x1 = x0 + 1, y1 = y0 + 1;
            float aw = w[l * 4 + pt] * inv;

            int x0c = min(max(x0, 0), ww - 1), x1c = min(max(x1, 0), ww - 1);
            int y0c = min(max(y0, 0), hh - 1), y1c = min(max(y1, 0), hh - 1);
            float w00 = aw * (1.f - wx) * (1.f - wy);
            float w10 = aw * wx * (1.f - wy);
            float w01 = aw * (1.f - wx) * wy;
            float w11 = aw * wx * wy;
            if (!(x0 >= 0 && x0 < ww)) { w00 = 0.f; w01 = 0.f; }
            if (!(x1 >= 0 && x1 < ww)) { w10 = 0.f; w11 = 0.f; }
            if (!(y0 >= 0 && y0 < hh)) { w00 = 0.f; w10 = 0.f; }
            if (!(y1 >= 0 && y1 < hh)) { w01 = 0.f; w11 = 0.f; }

            uint4 u00 = *(const uint4*)(vbase + (size_t)(start + y0c * ww + x0c) * 256);
            uint4 u10 = *(const uint4*)(vbase + (size_t)(start + y0c * ww + x1c) * 256);
            uint4 u01 = *(const uint4*)(vbase + (size_t)(start + y1c * ww + x0c) * 256);
            uint4 u11 = *(const uint4*)(vbase + (size_t)(start + y1c * ww + x1c) * 256);

#define ACC4(u, wgt) \
            acc[0] = fmaf(wgt, bf_lo(u.x), acc[0]); \
            acc[1] = fmaf(wgt, bf_hi(u.x), acc[1]); \
            acc[2] = fmaf(wgt, bf_lo(u.y), acc[2]); \
            acc[3] = fmaf(wgt, bf_hi(u.y), acc[3]); \
            acc[4] = fmaf(wgt, bf_lo(u.z), acc[4]); \
            acc[5] = fmaf(wgt, bf_hi(u.z), acc[5]); \
            acc[6] = fmaf(wgt, bf_lo(u.w), acc[6]); \
            acc[7] = fmaf(wgt, bf_hi(u.w), acc[7]);
            ACC4(u00, w00); ACC4(u10, w10); ACC4(u01, w01); ACC4(u11, w11);
#undef ACC4
        }
        start += hh * ww;
    }

    uint4 pk;
    pk.x = pack2(acc[0], acc[1]); pk.y = pack2(acc[2], acc[3]);
    pk.z = pack2(acc[4], acc[5]); pk.w = pack2(acc[6], acc[7]);
    *(uint4*)(sampled + (size_t)unit * 256 + h * 32 + c8 * 8) = pk;
}

// ---------------------------------------------------------------------------
extern "C" void kernel_launch(void* const* d_in, const int* in_sizes, int n_in,
                              void* d_out, int out_size, void* d_ws, size_t ws_size,
                              hipStream_t stream)
{
    (void)in_sizes; (void)n_in; (void)out_size; (void)ws_size;

    const float* tgt        = (const float*)d_in[0];
    const float* query_pos  = (const float*)d_in[1];
    const float* refp       = (const float*)d_in[2];
    const float* src        = (const float*)d_in[3];
    const float* w_in_intra = (const float*)d_in[4];
    const float* b_in_intra = (const float*)d_in[5];
    const float* w_out_intra= (const float*)d_in[6];
    const float* b_out_intra= (const float*)d_in[7];
    const float* g_ln_intra = (const float*)d_in[8];
    const float* b_ln_intra = (const float*)d_in[9];
    const float* w_in_inter = (const float*)d_in[10];
    const float* b_in_inter = (const float*)d_in[11];
    const float* w_out_inter= (const float*)d_in[12];
    const float* b_out_inter= (const float*)d_in[13];
    const float* g_ln_inter = (const float*)d_in[14];
    const float* b_ln_inter = (const float*)d_in[15];
    const float* off_w      = (const float*)d_in[16];
    const float* off_b      = (const float*)d_in[17];
    const float* aw_w       = (const float*)d_in[18];
    const float* aw_b       = (const float*)d_in[19];
    const float* val_w      = (const float*)d_in[20];
    const float* val_b      = (const float*)d_in[21];
    const float* co_w       = (const float*)d_in[22];
    const float* co_b       = (const float*)d_in[23];
    const float* g_ln_cross = (const float*)d_in[24];
    const float* b_ln_cross = (const float*)d_in[25];
    const float* lin1_w     = (const float*)d_in[26];
    const float* lin1_b     = (const float*)d_in[27];
    const float* lin2_w     = (const float*)d_in[28];
    const float* lin2_b     = (const float*)d_in[29];
    const float* g_ln3      = (const float*)d_in[30];
    const float* b_ln3      = (const float*)d_in[31];

    // Workspace layout (float units). Total ~37.4M floats = 150 MB.
    float* ws    = (float*)d_ws;
    float* qkv   = ws;                     // 7,680,000 fp32
    float* tmp   = ws + 7680000;           // 2,560,000 fp32
    u16*   attnb = (u16*)(ws + 10240000);  // 2,560,000 u16
    float* tgt1  = ws + 11520000;          // 2,560,000 fp32 (later: offsets)
    float* ti    = ws + 14080000;          // 2,560,000 fp32 (later: tgt2)
    u16*   tib   = (u16*)(ws + 16640000);  // 2,560,000 u16 (later: tgt2b)
    float* tA    = ws + 17920000;          // 2,560,000 fp32
    u16*   qcb   = (u16*)(ws + 20480000);  // 2,560,000 u16
    u16*   x1b   = (u16*)(ws + 21760000);  // 2,560,000 u16
    u16*   tgtb  = (u16*)(ws + 23040000);  // 2,560,000 u16
    float* awl   = ws + 24320000;          // 1,280,000 fp32
    u16*   valueb= (u16*)(ws + 25600000);  // 22,282,240 u16 (hidden overlays)
    u16*   wb    = (u16*)(ws + 36741120);  // 1,277,952 u16
    float* out   = (float*)d_out;

    // bf16 weight segment offsets in wb
    u16* wb_in_intra  = wb;
    u16* wb_out_intra = wb + 196608;
    u16* wb_in_inter  = wb + 262144;
    u16* wb_out_inter = wb + 458752;
    u16* wb_off       = wb + 524288;
    u16* wb_aw        = wb + 589824;
    u16* wb_val       = wb + 622592;
    u16* wb_co        = wb + 688128;
    u16* wb_lin1      = wb + 753664;
    u16* wb_lin2      = wb + 1015808;

    const float scale = 0.17677669529663687f;  // 1/sqrt(32)
    const int MB10K = (M10K + 63) / 64;        // 157

    // ---- one-shot conversions ----
    convert_weights_kernel<<<624, 256, 0, stream>>>(
        w_in_intra, w_out_intra, w_in_inter, w_out_inter, off_w,
        aw_w, val_w, co_w, lin1_w, lin2_w, wb);
    add_convert_kernel<<<1250, 256, 0, stream>>>(tgt, query_pos, x1b, tgtb, 320000);

    // ---- intra-instance self-attention (over 25 control points) ----
    gemm_mfma_kernel<<<dim3(8, MB10K), 256, 0, stream>>>(x1b, 1, 256, wb_in_intra, 256,
                                                         b_in_intra, qkv, 768, M10K, 0, 0);
    gemm_mfma_kernel<<<dim3(4, MB10K), 256, 0, stream>>>(tgtb, 1, 256, wb_in_intra + 512 * 256, 256,
                                                         b_in_intra + 512, qkv + 512, 768, M10K, 0, 0);
    small_attn_kernel<<<dim3(400, 8), 64, 25 * 64 * 4, stream>>>(qkv, attnb, 25, scale);
    gemm_mfma_kernel<<<dim3(4, MB10K), 256, 0, stream>>>(attnb, 1, 256, wb_out_intra, 256,
                                                         b_out_intra, tmp, 256, M10K, 0, 0);
    add_ln_kernel<<<M10K, 64, 0, stream>>>(tgt, tmp, g_ln_intra, b_ln_intra, tgt1, (u16*)0, 0);

    // ---- inter-instance self-attention (over 100 queries) ----
    tgt_to_ti_kernel<<<M10K, 64, 0, stream>>>(tgt1, ti, tib);
    gemm_mfma_kernel<<<dim3(12, MB10K), 256, 0, stream>>>(tib, 1, 256, wb_in_inter, 256,
                                                          b_in_inter, qkv, 768, M10K, 0, 0);
    small_attn_kernel<<<dim3(100, 8), 128, 100 * 64 * 4, stream>>>(qkv, attnb, 100, scale);
    gemm_mfma_kernel<<<dim3(4, MB10K), 256, 0, stream>>>(attnb, 1, 256, wb_out_inter, 256,
                                                         b_out_inter, tmp, 256, M10K, 0, 0);
    add_ln_kernel<<<M10K, 64, 0, stream>>>(ti, tmp, g_ln_inter, b_ln_inter, tA, (u16*)0, 1);

    // ---- deformable cross-attention ----
    add_convert_kernel<<<1250, 256, 0, stream>>>(tA, query_pos, qcb, (u16*)0, 320000);
    gemm_mfma_kernel<<<dim3(4, 1360), 256, 0, stream>>>(src, 0, 256, wb_val, 256,
                                                        val_b, valueb, 256, MVAL, 0, 1);
    gemm_mfma_kernel<<<dim3(4, MB10K), 256, 0, stream>>>(qcb, 1, 256, wb_off, 256,
                                                         off_b, tgt1, 256, M10K, 0, 0);   // offsets
    gemm_mfma_kernel<<<dim3(2, MB10K), 256, 0, stream>>>(qcb, 1, 256, wb_aw, 256,
                                                         aw_b, awl, 128, M10K, 0, 0);     // aw logits
    msdeform_sample_kernel<<<1250, 256, 0, stream>>>(valueb, tgt1, awl, refp, attnb);
    gemm_mfma_kernel<<<dim3(4, MB10K), 256, 0, stream>>>(attnb, 1, 256, wb_co, 256,
                                                         co_b, tmp, 256, M10K, 0, 0);
    add_ln_kernel<<<M10K, 64, 0, stream>>>(tA, tmp, g_ln_cross, b_ln_cross, ti, tib, 0);  // tgt2

    // ---- FFN ----
    gemm_mfma_kernel<<<dim3(16, MB10K), 256, 0, stream>>>(tib, 1, 256, wb_lin1, 256,
                                                          lin1_b, valueb, 1024, M10K, 1, 1); // hidden bf16
    gemm_mfma_kernel<<<dim3(4, MB10K), 256, 0, stream>>>(valueb, 1, 1024, wb_lin2, 1024,
                                                         lin2_b, tmp, 256, M10K, 0, 0);
    add_ln_kernel<<<M10K, 64, 0, stream>>>(ti, tmp, g_ln3, b_ln3, out, (u16*)0, 0);
}

// Round 5
// 524.234 us; speedup vs baseline: 2.2877x; 1.0727x over previous
//
#include <hip/hip_runtime.h>
#include <math.h>

// Problem constants
#define DMODEL 256
#define HEADS  8
#define HDIM   32
#define BS     4
#define NQ     100
#define NPTS   25
#define LQ     2500      // NQ*NPTS
#define M10K   10000     // BS*LQ
#define LEN_IN 21760
#define MVAL   87040     // BS*LEN_IN

typedef float f32x4 __attribute__((ext_vector_type(4)));
typedef short s16x8 __attribute__((ext_vector_type(8)));
typedef unsigned short u16;

// fp32 -> bf16 round-to-nearest-even
static __device__ __forceinline__ short f2bf(float f) {
    unsigned u = __builtin_bit_cast(unsigned, f);
    u = (u + 0x7fffu + ((u >> 16) & 1u)) >> 16;
    return (short)u;
}
static __device__ __forceinline__ unsigned pack2(float lo, float hi) {
    return (unsigned)(u16)f2bf(lo) | ((unsigned)(u16)f2bf(hi) << 16);
}
static __device__ __forceinline__ float bf_lo(unsigned u) {
    return __builtin_bit_cast(float, u << 16);
}
static __device__ __forceinline__ float bf_hi(unsigned u) {
    return __builtin_bit_cast(float, u & 0xffff0000u);
}

// ---------------------------------------------------------------------------
// One-shot weight conversion: 10 fp32 weight matrices -> concatenated bf16.
// ---------------------------------------------------------------------------
__global__ __launch_bounds__(256) void convert_weights_kernel(
    const float* __restrict__ s0, const float* __restrict__ s1,
    const float* __restrict__ s2, const float* __restrict__ s3,
    const float* __restrict__ s4, const float* __restrict__ s5,
    const float* __restrict__ s6, const float* __restrict__ s7,
    const float* __restrict__ s8, const float* __restrict__ s9,
    u16* __restrict__ dst)
{
    int t8 = (blockIdx.x * 256 + threadIdx.x) * 8;
    if (t8 >= 1277952) return;
    const float* s; int base;
    if      (t8 <  196608) { s = s0; base = 0;       }
    else if (t8 <  262144) { s = s1; base = 196608;  }
    else if (t8 <  458752) { s = s2; base = 262144;  }
    else if (t8 <  524288) { s = s3; base = 458752;  }
    else if (t8 <  589824) { s = s4; base = 524288;  }
    else if (t8 <  622592) { s = s5; base = 589824;  }
    else if (t8 <  688128) { s = s6; base = 622592;  }
    else if (t8 <  753664) { s = s7; base = 688128;  }
    else if (t8 < 1015808) { s = s8; base = 753664;  }
    else                   { s = s9; base = 1015808; }
    const float* p = s + (t8 - base);
    float4 a = *(const float4*)p;
    float4 b = *(const float4*)(p + 4);
    s16x8 v;
    v[0]=f2bf(a.x); v[1]=f2bf(a.y); v[2]=f2bf(a.z); v[3]=f2bf(a.w);
    v[4]=f2bf(b.x); v[5]=f2bf(b.y); v[6]=f2bf(b.z); v[7]=f2bf(b.w);
    *(s16x8*)(dst + t8) = v;
}

// ---------------------------------------------------------------------------
// xb = bf16(a + b) (b optional); ab = bf16(a) (optional). 8 elems/thread.
// ---------------------------------------------------------------------------
__global__ __launch_bounds__(256) void add_convert_kernel(
    const float* __restrict__ a, const float* __restrict__ b,
    u16* __restrict__ xb, u16* __restrict__ ab, int n8)
{
    int i = blockIdx.x * 256 + threadIdx.x;
    if (i >= n8) return;
    size_t o = (size_t)i * 8;
    float4 a0 = *(const float4*)(a + o);
    float4 a1 = *(const float4*)(a + o + 4);
    if (ab) {
        s16x8 v;
        v[0]=f2bf(a0.x); v[1]=f2bf(a0.y); v[2]=f2bf(a0.z); v[3]=f2bf(a0.w);
        v[4]=f2bf(a1.x); v[5]=f2bf(a1.y); v[6]=f2bf(a1.z); v[7]=f2bf(a1.w);
        *(s16x8*)(ab + o) = v;
    }
    if (b) {
        float4 b0 = *(const float4*)(b + o);
        float4 b1 = *(const float4*)(b + o + 4);
        a0.x += b0.x; a0.y += b0.y; a0.z += b0.z; a0.w += b0.w;
        a1.x += b1.x; a1.y += b1.y; a1.z += b1.z; a1.w += b1.w;
    }
    s16x8 v;
    v[0]=f2bf(a0.x); v[1]=f2bf(a0.y); v[2]=f2bf(a0.z); v[3]=f2bf(a0.w);
    v[4]=f2bf(a1.x); v[5]=f2bf(a1.y); v[6]=f2bf(a1.z); v[7]=f2bf(a1.w);
    *(s16x8*)(xb + o) = v;
}

// ---------------------------------------------------------------------------
// bf16-MFMA GEMM: C[M,N] = A[M,K] @ W[N,K]^T + bias[N].
// ---------------------------------------------------------------------------
#define LDSK 40   // padded bf16 row stride (zero bank conflicts, measured)

__global__ __launch_bounds__(256) void gemm_mfma_kernel(
    const void* __restrict__ Av, int a_bf16, int lda,
    const u16* __restrict__ W, int K,
    const float* __restrict__ bias,
    void* __restrict__ Cv, int ldc,
    int M, int relu, int out_bf16)
{
    __shared__ short As[64 * LDSK];
    __shared__ short Ws[64 * LDSK];

    const int tid = threadIdx.x;
    const int m0 = blockIdx.y * 64, n0 = blockIdx.x * 64;

    const int srow = tid >> 2;
    const int skseg = (tid & 3) * 8;

    const int wave = tid >> 6;
    const int wm = wave & 1, wn = wave >> 1;
    const int lane = tid & 63;
    const int lrow = lane & 15;
    const int kq = lane >> 4;

    f32x4 acc[2][2];
#pragma unroll
    for (int i = 0; i < 2; ++i)
#pragma unroll
        for (int j = 0; j < 2; ++j) acc[i][j] = (f32x4)(0.f);

    for (int k0 = 0; k0 < K; k0 += 32) {
        int gm = m0 + srow;
        s16x8 av = (s16x8)0;
        if (a_bf16) {
            if (gm < M)
                av = *(const s16x8*)((const u16*)Av + (size_t)gm * lda + k0 + skseg);
        } else {
            if (gm < M) {
                const float* ap = (const float*)Av + (size_t)gm * lda + k0 + skseg;
                float4 a0 = *(const float4*)ap;
                float4 a1 = *(const float4*)(ap + 4);
                av[0]=f2bf(a0.x); av[1]=f2bf(a0.y); av[2]=f2bf(a0.z); av[3]=f2bf(a0.w);
                av[4]=f2bf(a1.x); av[5]=f2bf(a1.y); av[6]=f2bf(a1.z); av[7]=f2bf(a1.w);
            }
        }
        s16x8 wv = *(const s16x8*)(W + (size_t)(n0 + srow) * K + k0 + skseg);
        *(s16x8*)&As[srow * LDSK + skseg] = av;
        *(s16x8*)&Ws[srow * LDSK + skseg] = wv;
        __syncthreads();

        s16x8 af[2], bf[2];
#pragma unroll
        for (int i = 0; i < 2; ++i)
            af[i] = *(const s16x8*)&As[(wm * 32 + i * 16 + lrow) * LDSK + kq * 8];
#pragma unroll
        for (int j = 0; j < 2; ++j)
            bf[j] = *(const s16x8*)&Ws[(wn * 32 + j * 16 + lrow) * LDSK + kq * 8];
#pragma unroll
        for (int i = 0; i < 2; ++i)
#pragma unroll
            for (int j = 0; j < 2; ++j)
                acc[i][j] = __builtin_amdgcn_mfma_f32_16x16x32_bf16(af[i], bf[j], acc[i][j], 0, 0, 0);
        __syncthreads();
    }

    // epilogue: C/D layout col=lane&15, row=kq*4+reg
#pragma unroll
    for (int i = 0; i < 2; ++i) {
#pragma unroll
        for (int j = 0; j < 2; ++j) {
            int col = n0 + wn * 32 + j * 16 + lrow;
            float bv = bias[col];
#pragma unroll
            for (int reg = 0; reg < 4; ++reg) {
                int gm = m0 + wm * 32 + i * 16 + kq * 4 + reg;
                if (gm < M) {
                    float v = acc[i][j][reg] + bv;
                    if (relu) v = fmaxf(v, 0.f);
                    if (out_bf16)
                        ((u16*)Cv)[(size_t)gm * ldc + col] = (u16)f2bf(v);
                    else
                        ((float*)Cv)[(size_t)gm * ldc + col] = v;
                }
            }
        }
    }
}

// ---------------------------------------------------------------------------
// Inter attention (S=100). Block = 512 threads per (b,h); thread =
// (kc = key-chunk 0..3, r = row 0..127, active r<100). Each thread runs a
// 25-step online-softmax over its key chunk; partials combined via LDS
// (flash combine). O padded to stride 33 to avoid r*32 bank collisions.
// qkv: fp32 [100, 100, 768]; out: bf16 [100, 100, 256].
// ---------------------------------------------------------------------------
__global__ __launch_bounds__(512) void inter_attn_kernel(
    const float* __restrict__ qkv, u16* __restrict__ out, float scale)
{
    __shared__ float4 Kv[100][16];     // [row]: K f4 0..7 | V f4 8..15 (25.6 KB)
    __shared__ float4 Ml4[100];        // per-row 4 chunk maxes
    __shared__ float4 Ll4[100];        // per-row 4 chunk sums
    __shared__ float  O[100][33];      // padded accumulator (13.2 KB)

    const int b = blockIdx.x, h = blockIdx.y;
    const float* base = qkv + (size_t)b * 100 * 768;
    const int tid = threadIdx.x;
    const int r = tid & 127, kc = tid >> 7;

    // stage K/V for this head
    for (int idx = tid; idx < 1600; idx += 512) {
        int row = idx >> 4, seg = idx & 15;
        const float* src = (seg < 8)
            ? base + row * 768 + 256 + h * 32 + seg * 4
            : base + row * 768 + 512 + h * 32 + (seg - 8) * 4;
        Kv[row][seg] = *(const float4*)src;
    }
    // zero O
    for (int idx = tid; idx < 100 * 33; idx += 512)
        ((float*)O)[idx] = 0.f;

    float q[32];
    if (r < 100) {
        const float* qp = base + r * 768 + h * 32;
#pragma unroll
        for (int c4 = 0; c4 < 8; ++c4) {
            float4 f = *(const float4*)(qp + c4 * 4);
            q[c4*4+0] = f.x; q[c4*4+1] = f.y; q[c4*4+2] = f.z; q[c4*4+3] = f.w;
        }
    }
    __syncthreads();

    float m = -1e30f, l = 0.f, acc[32];
#pragma unroll
    for (int c = 0; c < 32; ++c) acc[c] = 0.f;

    if (r < 100) {
        const int j0 = kc * 25;
#pragma unroll 2
        for (int s = 0; s < 25; ++s) {
            const float4* kr = &Kv[j0 + s][0];
            float dot = 0.f;
#pragma unroll
            for (int c4 = 0; c4 < 8; ++c4) {
                float4 kf = kr[c4];
                dot = fmaf(q[c4*4+0], kf.x, dot);
                dot = fmaf(q[c4*4+1], kf.y, dot);
                dot = fmaf(q[c4*4+2], kf.z, dot);
                dot = fmaf(q[c4*4+3], kf.w, dot);
            }
            dot *= scale;
            float mn = fmaxf(m, dot);
            float alpha = __expf(m - mn);
            float p = __expf(dot - mn);
            l = l * alpha + p;
            const float4* vr = &Kv[j0 + s][8];
#pragma unroll
            for (int c4 = 0; c4 < 8; ++c4) {
                float4 vf = vr[c4];
                acc[c4*4+0] = acc[c4*4+0] * alpha + p * vf.x;
                acc[c4*4+1] = acc[c4*4+1] * alpha + p * vf.y;
                acc[c4*4+2] = acc[c4*4+2] * alpha + p * vf.z;
                acc[c4*4+3] = acc[c4*4+3] * alpha + p * vf.w;
            }
            m = mn;
        }
        ((float*)&Ml4[r])[kc] = m;
        ((float*)&Ll4[r])[kc] = l;
    }
    __syncthreads();

    float alphaK = 0.f, Ltot = 1.f;
    if (r < 100) {
        float4 mv = Ml4[r];
        float4 lv = Ll4[r];
        float M = fmaxf(fmaxf(mv.x, mv.y), fmaxf(mv.z, mv.w));
        Ltot = __expf(mv.x - M) * lv.x + __expf(mv.y - M) * lv.y
             + __expf(mv.z - M) * lv.z + __expf(mv.w - M) * lv.w;
        alphaK = __expf(m - M);
    }
    // sequential chunk accumulation (4 rounds, uniform barrier)
    for (int cc = 0; cc < 4; ++cc) {
        if (kc == cc && r < 100) {
#pragma unroll
            for (int c = 0; c < 32; ++c) O[r][c] += alphaK * acc[c];
        }
        __syncthreads();
    }
    if (kc == 0 && r < 100) {
        float inv = 1.f / Ltot;
        unsigned* op = (unsigned*)(out + ((size_t)b * 100 + r) * 256 + h * 32);
#pragma unroll
        for (int c = 0; c < 16; ++c)
            op[c] = pack2(O[r][2*c] * inv, O[r][2*c+1] * inv);
    }
}

// ---------------------------------------------------------------------------
// Intra attention (S=25). Block = 256 threads per batch-block b; thread =
// (h = t>>5, r = t&31, active r<25). K/V for ALL heads staged via one
// contiguous 512-float row copy. 25-step online softmax, full lanes.
// qkv: fp32 [400, 25, 768]; out: bf16 [400, 25, 256].
// ---------------------------------------------------------------------------
__global__ __launch_bounds__(256) void intra_attn_kernel(
    const float* __restrict__ qkv, u16* __restrict__ out, float scale)
{
    __shared__ float4 KV[25][128];   // [row]: K all heads (64 f4) | V (64 f4)

    const int b = blockIdx.x;
    const int h = threadIdx.x >> 5, r = threadIdx.x & 31;
    const float* base = qkv + (size_t)b * 25 * 768;

    for (int idx = threadIdx.x; idx < 3200; idx += 256) {
        int row = idx >> 7, c = idx & 127;
        KV[row][c] = *(const float4*)(base + row * 768 + 256 + c * 4);
    }

    float q[32];
    if (r < 25) {
        const float* qp = base + r * 768 + h * 32;
#pragma unroll
        for (int c4 = 0; c4 < 8; ++c4) {
            float4 f = *(const float4*)(qp + c4 * 4);
            q[c4*4+0] = f.x; q[c4*4+1] = f.y; q[c4*4+2] = f.z; q[c4*4+3] = f.w;
        }
    }
    __syncthreads();

    if (r < 25) {
        float m = -1e30f, l = 0.f, acc[32];
#pragma unroll
        for (int c = 0; c < 32; ++c) acc[c] = 0.f;
#pragma unroll 2
        for (int j = 0; j < 25; ++j) {
            const float4* kr = &KV[j][h * 8];
            float dot = 0.f;
#pragma unroll
            for (int c4 = 0; c4 < 8; ++c4) {
                float4 kf = kr[c4];
                dot = fmaf(q[c4*4+0], kf.x, dot);
                dot = fmaf(q[c4*4+1], kf.y, dot);
                dot = fmaf(q[c4*4+2], kf.z, dot);
                dot = fmaf(q[c4*4+3], kf.w, dot);
            }
            dot *= scale;
            float mn = fmaxf(m, dot);
            float alpha = __expf(m - mn);
            float p = __expf(dot - mn);
            l = l * alpha + p;
            const float4* vr = &KV[j][64 + h * 8];
#pragma unroll
            for (int c4 = 0; c4 < 8; ++c4) {
                float4 vf = vr[c4];
                acc[c4*4+0] = acc[c4*4+0] * alpha + p * vf.x;
                acc[c4*4+1] = acc[c4*4+1] * alpha + p * vf.y;
                acc[c4*4+2] = acc[c4*4+2] * alpha + p * vf.z;
                acc[c4*4+3] = acc[c4*4+3] * alpha + p * vf.w;
            }
            m = mn;
        }
        float inv = 1.f / l;
        unsigned* op = (unsigned*)(out + ((size_t)b * 25 + r) * 256 + h * 32);
#pragma unroll
        for (int c = 0; c < 16; ++c)
            op[c] = pack2(acc[2*c] * inv, acc[2*c+1] * inv);
    }
}

// ---------------------------------------------------------------------------
// out[row] = LN(a[row] + b[row]) * g + beta; optional bf16 mirror out_bf.
// ---------------------------------------------------------------------------
__global__ __launch_bounds__(64) void add_ln_kernel(
    const float* __restrict__ a, const float* __restrict__ b,
    const float* __restrict__ g, const float* __restrict__ beta,
    float* __restrict__ out, u16* __restrict__ out_bf, int transpose_mode)
{
    const int r = blockIdx.x;
    const int lane = threadIdx.x;
    const float* ar = a + (size_t)r * 256;
    const float* br = b + (size_t)r * 256;
    float x[4];
    float s = 0.f;
#pragma unroll
    for (int i = 0; i < 4; ++i) {
        x[i] = ar[lane + 64 * i] + br[lane + 64 * i];
        s += x[i];
    }
#pragma unroll
    for (int off = 32; off >= 1; off >>= 1) s += __shfl_xor(s, off);
    float mean = s * (1.f / 256.f);
    float vs = 0.f;
#pragma unroll
    for (int i = 0; i < 4; ++i) { float d = x[i] - mean; vs += d * d; }
#pragma unroll
    for (int off = 32; off >= 1; off >>= 1) vs += __shfl_xor(vs, off);
    float rstd = rsqrtf(vs * (1.f / 256.f) + 1e-5f);

    size_t ro = r;
    if (transpose_mode) {
        int q = r % 100; int bp = r / 100; int p = bp % 25; int bb = bp / 25;
        ro = ((size_t)bb * 100 + q) * 25 + p;
    }
    float* orow = out + ro * 256;
    u16* brow = out_bf ? out_bf + ro * 256 : (u16*)0;
#pragma unroll
    for (int i = 0; i < 4; ++i) {
        int c = lane + 64 * i;
        float v = (x[i] - mean) * rstd * g[c] + beta[c];
        orow[c] = v;
        if (brow) brow[c] = (u16)f2bf(v);
    }
}

// ---------------------------------------------------------------------------
// ti[(b*25+p)*100+q][:] = tgt1[(b*100+q)*25+p][:]  (fp32 + bf16 mirror)
// ---------------------------------------------------------------------------
__global__ __launch_bounds__(64) void tgt_to_ti_kernel(
    const float* __restrict__ tgt1, float* __restrict__ ti, u16* __restrict__ tib)
{
    const int r = blockIdx.x;              // ti row
    int q = r % 100; int bp = r / 100; int p = bp % 25; int b = bp / 25;
    const float4* srcp = (const float4*)(tgt1 + (((size_t)b * 100 + q) * 25 + p) * 256);
    float4 v = srcp[threadIdx.x];
    ((float4*)(ti + (size_t)r * 256))[threadIdx.x] = v;
    uint2 pk = make_uint2(pack2(v.x, v.y), pack2(v.z, v.w));
    ((uint2*)(tib + (size_t)r * 256))[threadIdx.x] = pk;
}

// ---------------------------------------------------------------------------
// MSDeform sampling, bf16 value, 8 channels/thread, bf16 output.
// Point loop NOT unrolled (full unroll spilled: VGPR=256, 102 MB scratch).
// ---------------------------------------------------------------------------
__global__ __launch_bounds__(256, 4) void msdeform_sample_kernel(
    const u16* __restrict__ value,
    const float* __restrict__ off,
    const float* __restrict__ awl,
    const float* __restrict__ refp,
    u16* __restrict__ sampled)
{
    const int unit = blockIdx.x * 8 + (threadIdx.x >> 5);
    const int t = threadIdx.x & 31;
    const int h = t >> 2, c8 = t & 3;
    const int b = unit / LQ, lq = unit - b * LQ;
    const int q = lq / NPTS;

    const float* awp = awl + (size_t)unit * 128 + h * 16;
    float w[16];
    float mx = -1e30f;
#pragma unroll
    for (int k = 0; k < 16; ++k) { w[k] = awp[k]; mx = fmaxf(mx, w[k]); }
    float sum = 0.f;
#pragma unroll
    for (int k = 0; k < 16; ++k) { w[k] = __expf(w[k] - mx); sum += w[k]; }
    const float inv = 1.f / sum;

    const float* offp = off + (size_t)unit * 256 + h * 32;
    const float* rp = refp + ((size_t)b * 100 + q) * 8;
    const u16* vbase = value + (size_t)b * LEN_IN * 256 + h * 32 + c8 * 8;

    float acc[8];
#pragma unroll
    for (int k = 0; k < 8; ++k) acc[k] = 0.f;

    int start = 0;
    const int sz[4] = {128, 64, 32, 16};
#pragma unroll
    for (int l = 0; l < 4; ++l) {
        const int hh = sz[l], ww = sz[l];
        const float rx = rp[l * 2 + 0], ry = rp[l * 2 + 1];
#pragma unroll 1
        for (int pt = 0; pt < 4; ++pt) {
            float ox = offp[(l * 4 + pt) * 2 + 0];
            float oy = offp[(l * 4 + pt) * 2 + 1];
            float x = rx * ww + ox - 0.5f;
            float y = ry * hh + oy - 0.5f;
            float x0f = floorf(x), y0f = floorf(y);
            float wx = x - x0f, wy = y - y0f;
            int x0 = (int)x0f, y0 = (int)y0f;
            int x1 = x0 + 1, y1 = y0 + 1;
            float aw = w[l * 4 + pt] * inv;

            int x0c = min(max(x0, 0), ww - 1), x1c = min(max(x1, 0), ww - 1);
            int y0c = min(max(y0, 0), hh - 1), y1c = min(max(y1, 0), hh - 1);
            float w00 = aw * (1.f - wx) * (1.f - wy);
            float w10 = aw * wx * (1.f - wy);
            float w01 = aw * (1.f - wx) * wy;
            float w11 = aw * wx * wy;
            if (!(x0 >= 0 && x0 < ww)) { w00 = 0.f; w01 = 0.f; }
            if (!(x1 >= 0 && x1 < ww)) { w10 = 0.f; w11 = 0.f; }
            if (!(y0 >= 0 && y0 < hh)) { w00 = 0.f; w10 = 0.f; }
            if (!(y1 >= 0 && y1 < hh)) { w01 = 0.f; w11 = 0.f; }

            uint4 u00 = *(const uint4*)(vbase + (size_t)(start + y0c * ww + x0c) * 256);
            uint4 u10 = *(const uint4*)(vbase + (size_t)(start + y0c * ww + x1c) * 256);
            uint4 u01 = *(const uint4*)(vbase + (size_t)(start + y1c * ww + x0c) * 256);
            uint4 u11 = *(const uint4*)(vbase + (size_t)(start + y1c * ww + x1c) * 256);

#define ACC4(u, wgt) \
            acc[0] = fmaf(wgt, bf_lo(u.x), acc[0]); \
            acc[1] = fmaf(wgt, bf_hi(u.x), acc[1]); \
            acc[2] = fmaf(wgt, bf_lo(u.y), acc[2]); \
            acc[3] = fmaf(wgt, bf_hi(u.y), acc[3]); \
            acc[4] = fmaf(wgt, bf_lo(u.z), acc[4]); \
            acc[5] = fmaf(wgt, bf_hi(u.z), acc[5]); \
            acc[6] = fmaf(wgt, bf_lo(u.w), acc[6]); \
            acc[7] = fmaf(wgt, bf_hi(u.w), acc[7]);
            ACC4(u00, w00); ACC4(u10, w10); ACC4(u01, w01); ACC4(u11, w11);
#undef ACC4
        }
        start += hh * ww;
    }

    uint4 pk;
    pk.x = pack2(acc[0], acc[1]); pk.y = pack2(acc[2], acc[3]);
    pk.z = pack2(acc[4], acc[5]); pk.w = pack2(acc[6], acc[7]);
    *(uint4*)(sampled + (size_t)unit * 256 + h * 32 + c8 * 8) = pk;
}

// ---------------------------------------------------------------------------
extern "C" void kernel_launch(void* const* d_in, const int* in_sizes, int n_in,
                              void* d_out, int out_size, void* d_ws, size_t ws_size,
                              hipStream_t stream)
{
    (void)in_sizes; (void)n_in; (void)out_size; (void)ws_size;

    const float* tgt        = (const float*)d_in[0];
    const float* query_pos  = (const float*)d_in[1];
    const float* refp       = (const float*)d_in[2];
    const float* src        = (const float*)d_in[3];
    const float* w_in_intra = (const float*)d_in[4];
    const float* b_in_intra = (const float*)d_in[5];
    const float* w_out_intra= (const float*)d_in[6];
    const float* b_out_intra= (const float*)d_in[7];
    const float* g_ln_intra = (const float*)d_in[8];
    const float* b_ln_intra = (const float*)d_in[9];
    const float* w_in_inter = (const float*)d_in[10];
    const float* b_in_inter = (const float*)d_in[11];
    const float* w_out_inter= (const float*)d_in[12];
    const float* b_out_inter= (const float*)d_in[13];
    const float* g_ln_inter = (const float*)d_in[14];
    const float* b_ln_inter = (const float*)d_in[15];
    const float* off_w      = (const float*)d_in[16];
    const float* off_b      = (const float*)d_in[17];
    const float* aw_w       = (const float*)d_in[18];
    const float* aw_b       = (const float*)d_in[19];
    const float* val_w      = (const float*)d_in[20];
    const float* val_b      = (const float*)d_in[21];
    const float* co_w       = (const float*)d_in[22];
    const float* co_b       = (const float*)d_in[23];
    const float* g_ln_cross = (const float*)d_in[24];
    const float* b_ln_cross = (const float*)d_in[25];
    const float* lin1_w     = (const float*)d_in[26];
    const float* lin1_b     = (const float*)d_in[27];
    const float* lin2_w     = (const float*)d_in[28];
    const float* lin2_b     = (const float*)d_in[29];
    const float* g_ln3      = (const float*)d_in[30];
    const float* b_ln3      = (const float*)d_in[31];

    // Workspace layout (float units). Total ~37.4M floats = 150 MB.
    float* ws    = (float*)d_ws;
    float* qkv   = ws;                     // 7,680,000 fp32
    float* tmp   = ws + 7680000;           // 2,560,000 fp32
    u16*   attnb = (u16*)(ws + 10240000);  // 2,560,000 u16
    float* tgt1  = ws + 11520000;          // 2,560,000 fp32 (later: offsets)
    float* ti    = ws + 14080000;          // 2,560,000 fp32 (later: tgt2)
    u16*   tib   = (u16*)(ws + 16640000);  // 2,560,000 u16 (later: tgt2b)
    float* tA    = ws + 17920000;          // 2,560,000 fp32
    u16*   qcb   = (u16*)(ws + 20480000);  // 2,560,000 u16
    u16*   x1b   = (u16*)(ws + 21760000);  // 2,560,000 u16
    u16*   tgtb  = (u16*)(ws + 23040000);  // 2,560,000 u16
    float* awl   = ws + 24320000;          // 1,280,000 fp32
    u16*   valueb= (u16*)(ws + 25600000);  // 22,282,240 u16 (hidden overlays)
    u16*   wb    = (u16*)(ws + 36741120);  // 1,277,952 u16
    float* out   = (float*)d_out;

    // bf16 weight segment offsets in wb
    u16* wb_in_intra  = wb;
    u16* wb_out_intra = wb + 196608;
    u16* wb_in_inter  = wb + 262144;
    u16* wb_out_inter = wb + 458752;
    u16* wb_off       = wb + 524288;
    u16* wb_aw        = wb + 589824;
    u16* wb_val       = wb + 622592;
    u16* wb_co        = wb + 688128;
    u16* wb_lin1      = wb + 753664;
    u16* wb_lin2      = wb + 1015808;

    const float scale = 0.17677669529663687f;  // 1/sqrt(32)
    const int MB10K = (M10K + 63) / 64;        // 157

    // ---- one-shot conversions ----
    convert_weights_kernel<<<624, 256, 0, stream>>>(
        w_in_intra, w_out_intra, w_in_inter, w_out_inter, off_w,
        aw_w, val_w, co_w, lin1_w, lin2_w, wb);
    add_convert_kernel<<<1250, 256, 0, stream>>>(tgt, query_pos, x1b, tgtb, 320000);

    // ---- intra-instance self-attention (over 25 control points) ----
    gemm_mfma_kernel<<<dim3(8, MB10K), 256, 0, stream>>>(x1b, 1, 256, wb_in_intra, 256,
                                                         b_in_intra, qkv, 768, M10K, 0, 0);
    gemm_mfma_kernel<<<dim3(4, MB10K), 256, 0, stream>>>(tgtb, 1, 256, wb_in_intra + 512 * 256, 256,
                                                         b_in_intra + 512, qkv + 512, 768, M10K, 0, 0);
    intra_attn_kernel<<<400, 256, 0, stream>>>(qkv, attnb, scale);
    gemm_mfma_kernel<<<dim3(4, MB10K), 256, 0, stream>>>(attnb, 1, 256, wb_out_intra, 256,
                                                         b_out_intra, tmp, 256, M10K, 0, 0);
    add_ln_kernel<<<M10K, 64, 0, stream>>>(tgt, tmp, g_ln_intra, b_ln_intra, tgt1, (u16*)0, 0);

    // ---- inter-instance self-attention (over 100 queries) ----
    tgt_to_ti_kernel<<<M10K, 64, 0, stream>>>(tgt1, ti, tib);
    gemm_mfma_kernel<<<dim3(12, MB10K), 256, 0, stream>>>(tib, 1, 256, wb_in_inter, 256,
                                                          b_in_inter, qkv, 768, M10K, 0, 0);
    inter_attn_kernel<<<dim3(100, 8), 512, 0, stream>>>(qkv, attnb, scale);
    gemm_mfma_kernel<<<dim3(4, MB10K), 256, 0, stream>>>(attnb, 1, 256, wb_out_inter, 256,
                                                         b_out_inter, tmp, 256, M10K, 0, 0);
    add_ln_kernel<<<M10K, 64, 0, stream>>>(ti, tmp, g_ln_inter, b_ln_inter, tA, (u16*)0, 1);

    // ---- deformable cross-attention ----
    add_convert_kernel<<<1250, 256, 0, stream>>>(tA, query_pos, qcb, (u16*)0, 320000);
    gemm_mfma_kernel<<<dim3(4, 1360), 256, 0, stream>>>(src, 0, 256, wb_val, 256,
                                                        val_b, valueb, 256, MVAL, 0, 1);
    gemm_mfma_kernel<<<dim3(4, MB10K), 256, 0, stream>>>(qcb, 1, 256, wb_off, 256,
                                                         off_b, tgt1, 256, M10K, 0, 0);   // offsets
    gemm_mfma_kernel<<<dim3(2, MB10K), 256, 0, stream>>>(qcb, 1, 256, wb_aw, 256,
                                                         aw_b, awl, 128, M10K, 0, 0);     // aw logits
    msdeform_sample_kernel<<<1250, 256, 0, stream>>>(valueb, tgt1, awl, refp, attnb);
    gemm_mfma_kernel<<<dim3(4, MB10K), 256, 0, stream>>>(attnb, 1, 256, wb_co, 256,
                                                         co_b, tmp, 256, M10K, 0, 0);
    add_ln_kernel<<<M10K, 64, 0, stream>>>(tA, tmp, g_ln_cross, b_ln_cross, ti, tib, 0);  // tgt2

    // ---- FFN ----
    gemm_mfma_kernel<<<dim3(16, MB10K), 256, 0, stream>>>(tib, 1, 256, wb_lin1, 256,
                                                          lin1_b, valueb, 1024, M10K, 1, 1); // hidden bf16
    gemm_mfma_kernel<<<dim3(4, MB10K), 256, 0, stream>>>(valueb, 1, 1024, wb_lin2, 1024,
                                                         lin2_b, tmp, 256, M10K, 0, 0);
    add_ln_kernel<<<M10K, 64, 0, stream>>>(ti, tmp, g_ln3, b_ln3, out, (u16*)0, 0);
}